// Round 1
// baseline (5565.583 us; speedup 1.0000x reference)
//
#include <hip/hip_runtime.h>
#include <cmath>

#define Nn 20000
#define Ee 320000

// ---------------- workspace layout (in floats) ----------------
static const size_t XL0  = 0;                    // N*512
static const size_t XR0  = XL0 + 10240000;       // N*512
static const size_t OUT0 = XR0 + 10240000;       // N*512 (h0 in-place after BN)
static const size_t XL1  = OUT0 + 10240000;      // N*256
static const size_t XR1  = XL1 + 5120000;        // N*256
static const size_t OUT1 = XR1 + 5120000;        // N*64  (h1 in-place after BN)
static const size_t E0S  = OUT1 + 1280000;       // E*4 scores -> exp in place
static const size_t E1S  = E0S + 1280000;        // E*4
static const size_t SM   = E1S + 1280000;        // small zero-init region start
static const size_t EMAX0 = SM;                  // 80000 (unsigned encoded)
static const size_t DEN0  = EMAX0 + 80000;       // 80000
static const size_t EMAX1 = DEN0 + 80000;        // 80000
static const size_t DEN1  = EMAX1 + 80000;       // 80000
static const size_t BN0S  = DEN1 + 80000;        // 512 sum + 512 sumsq
static const size_t BN1S  = BN0S + 1024;         // 64 sum + 64 sumsq
static const size_t POOLS = BN1S + 128;          // 64*64
static const size_t CNTS  = POOLS + 4096;        // 64
static const size_t SMALL_CNT = (CNTS + 64) - SM;
static const size_t Z1   = CNTS + 64;            // 64*256
static const size_t Z2   = Z1 + 16384;           // 64*128

// ---------------- helpers ----------------
__device__ __forceinline__ unsigned fenc(float f){
  unsigned u = __float_as_uint(f);
  return (u & 0x80000000u) ? ~u : (u | 0x80000000u);
}
__device__ __forceinline__ float fdec(unsigned u){
  return __uint_as_float((u & 0x80000000u) ? (u ^ 0x80000000u) : ~u);
}
__device__ __forceinline__ float lrelu(float x){ return x > 0.f ? x : 0.2f * x; }
__device__ __forceinline__ float elu(float x){ return x > 0.f ? x : expm1f(x); }

// ---------------- GEMM: O = A[M,K] @ W[K,Nc]; blockIdx.z picks (Wa->Oa)/(Wb->Ob)
__global__ __launch_bounds__(256) void gemm2(const float* __restrict__ A,
    const float* __restrict__ Wa, const float* __restrict__ Wb,
    float* __restrict__ Oa, float* __restrict__ Ob, int M, int K, int Nc){
  const float* W = blockIdx.z ? Wb : Wa;
  float* O = blockIdx.z ? Ob : Oa;
  __shared__ float As[64][17];   // [m][k], pad
  __shared__ float Ws[16][68];   // [k][n], pad 4 keeps float4 align
  int tid = threadIdx.x;
  int m0 = blockIdx.y * 64, n0 = blockIdx.x * 64;
  int tm = tid >> 4, tn = tid & 15;
  int ar = tid >> 2, ac = (tid & 3) * 4;
  int wr = tid >> 4, wc = (tid & 15) * 4;
  float acc[4][4] = {};
  for (int kt = 0; kt < K; kt += 16){
    float4 av = make_float4(0.f,0.f,0.f,0.f);
    int gr = m0 + ar;
    if (gr < M) av = *(const float4*)&A[(size_t)gr * K + kt + ac];
    As[ar][ac] = av.x; As[ar][ac+1] = av.y; As[ar][ac+2] = av.z; As[ar][ac+3] = av.w;
    float4 wv = *(const float4*)&W[(size_t)(kt + wr) * Nc + n0 + wc];
    *(float4*)&Ws[wr][wc] = wv;
    __syncthreads();
    #pragma unroll
    for (int k = 0; k < 16; k++){
      float a_[4];
      #pragma unroll
      for (int i = 0; i < 4; i++) a_[i] = As[tm*4 + i][k];
      float4 bv = *(float4*)&Ws[k][tn*4];
      float b_[4] = {bv.x, bv.y, bv.z, bv.w};
      #pragma unroll
      for (int i = 0; i < 4; i++)
        #pragma unroll
        for (int j = 0; j < 4; j++)
          acc[i][j] += a_[i] * b_[j];
    }
    __syncthreads();
  }
  #pragma unroll
  for (int i = 0; i < 4; i++){
    int row = m0 + tm*4 + i;
    if (row < M)
      *(float4*)&O[(size_t)row * Nc + n0 + tn*4] =
          make_float4(acc[i][0], acc[i][1], acc[i][2], acc[i][3]);
  }
}

// ---------------- layer-0 edge scores (512 ch, H=4,C=128), wave per edge
__global__ __launch_bounds__(256) void score_l0(const float* __restrict__ xl,
    const float* __restrict__ xr, const float* __restrict__ ea,
    const float* __restrict__ we, const float* __restrict__ att,
    const int* __restrict__ ei, float* __restrict__ esc, unsigned* __restrict__ emax){
  int eid = blockIdx.x * 4 + (threadIdx.x >> 6);
  int lane = threadIdx.x & 63;
  int src = ei[eid], dst = ei[Ee + eid];
  float a = ea[eid];
  int c = lane << 3;                       // 8 channels per lane
  const float4* lp = (const float4*)&xl[(size_t)src * 512 + c];
  const float4* rp = (const float4*)&xr[(size_t)dst * 512 + c];
  const float4* wp = (const float4*)&we[c];
  const float4* tp = (const float4*)&att[c];   // att flat idx == channel idx
  float p = 0.f;
  #pragma unroll
  for (int q = 0; q < 2; q++){
    float4 l = lp[q], r = rp[q], w = wp[q], t = tp[q];
    p += lrelu(l.x + r.x + a * w.x) * t.x;
    p += lrelu(l.y + r.y + a * w.y) * t.y;
    p += lrelu(l.z + r.z + a * w.z) * t.z;
    p += lrelu(l.w + r.w + a * w.w) * t.w;
  }
  p += __shfl_xor(p, 8); p += __shfl_xor(p, 4);
  p += __shfl_xor(p, 2); p += __shfl_xor(p, 1);
  if ((lane & 15) == 0){
    int h = lane >> 4;
    esc[eid * 4 + h] = p;
    atomicMax(&emax[dst * 4 + h], fenc(p));
  }
}

// ---------------- layer-1 edge scores (256 ch, H=4,C=64)
__global__ __launch_bounds__(256) void score_l1(const float* __restrict__ xl,
    const float* __restrict__ xr, const float* __restrict__ ea,
    const float* __restrict__ we, const float* __restrict__ att,
    const int* __restrict__ ei, float* __restrict__ esc, unsigned* __restrict__ emax){
  int eid = blockIdx.x * 4 + (threadIdx.x >> 6);
  int lane = threadIdx.x & 63;
  int src = ei[eid], dst = ei[Ee + eid];
  float a = ea[eid];
  int c = lane << 2;                       // 4 channels per lane
  float4 l = *(const float4*)&xl[(size_t)src * 256 + c];
  float4 r = *(const float4*)&xr[(size_t)dst * 256 + c];
  float4 w = *(const float4*)&we[c];
  float4 t = *(const float4*)&att[c];
  float p = 0.f;
  p += lrelu(l.x + r.x + a * w.x) * t.x;
  p += lrelu(l.y + r.y + a * w.y) * t.y;
  p += lrelu(l.z + r.z + a * w.z) * t.z;
  p += lrelu(l.w + r.w + a * w.w) * t.w;
  p += __shfl_xor(p, 8); p += __shfl_xor(p, 4);
  p += __shfl_xor(p, 2); p += __shfl_xor(p, 1);
  if ((lane & 15) == 0){
    int h = lane >> 4;
    esc[eid * 4 + h] = p;
    atomicMax(&emax[dst * 4 + h], fenc(p));
  }
}

// ---------------- exp(e - max) and denom accumulate; in-place on esc
__global__ __launch_bounds__(256) void exp_norm(float* __restrict__ esc,
    const unsigned* __restrict__ emax, float* __restrict__ den,
    const int* __restrict__ ei){
  int idx = blockIdx.x * 256 + threadIdx.x;   // < Ee*4
  int e = idx >> 2, h = idx & 3;
  int dst = ei[Ee + e];
  float v = expf(esc[idx] - fdec(emax[dst * 4 + h]));
  esc[idx] = v;
  atomicAdd(&den[dst * 4 + h], v);
}

// ---------------- layer-0 scatter: out[dst, hc] += alpha_h * xl[src, hc]
__global__ __launch_bounds__(256) void scatter_l0(const float* __restrict__ xl,
    const float* __restrict__ esc, const float* __restrict__ den,
    const int* __restrict__ ei, float* __restrict__ out){
  int eid = blockIdx.x * 4 + (threadIdx.x >> 6);
  int lane = threadIdx.x & 63;
  int src = ei[eid], dst = ei[Ee + eid];
  int h = lane >> 4, c = lane << 3;
  float alpha = esc[eid * 4 + h] / (den[dst * 4 + h] + 1e-16f);
  const float4* lp = (const float4*)&xl[(size_t)src * 512 + c];
  float4 v0 = lp[0], v1 = lp[1];
  float* op = &out[(size_t)dst * 512 + c];
  atomicAdd(op + 0, alpha * v0.x); atomicAdd(op + 1, alpha * v0.y);
  atomicAdd(op + 2, alpha * v0.z); atomicAdd(op + 3, alpha * v0.w);
  atomicAdd(op + 4, alpha * v1.x); atomicAdd(op + 5, alpha * v1.y);
  atomicAdd(op + 6, alpha * v1.z); atomicAdd(op + 7, alpha * v1.w);
}

// ---------------- layer-1 scatter with head-mean folded in: out[dst,c] += sum_h (a_h/4) xl[src,h*64+c]
__global__ __launch_bounds__(256) void scatter_l1(const float* __restrict__ xl,
    const float* __restrict__ esc, const float* __restrict__ den,
    const int* __restrict__ ei, float* __restrict__ out){
  int eid = blockIdx.x * 4 + (threadIdx.x >> 6);
  int lane = threadIdx.x & 63;                // = output channel
  int src = ei[eid], dst = ei[Ee + eid];
  float acc = 0.f;
  #pragma unroll
  for (int h = 0; h < 4; h++){
    float alpha = esc[eid * 4 + h] / (den[dst * 4 + h] + 1e-16f) * 0.25f;
    acc += alpha * xl[(size_t)src * 256 + h * 64 + lane];
  }
  atomicAdd(&out[(size_t)dst * 64 + lane], acc);
}

// ---------------- batchnorm reduce: stats[c]=sum, stats[C+c]=sumsq
__global__ void bn_reduce(const float* __restrict__ X, float* __restrict__ stats,
                          int Nr, int C, int rpb){
  int tid = threadIdx.x;
  int c = tid % C, sub = tid / C, step = blockDim.x / C;
  float s = 0.f, s2 = 0.f;
  int rend = min((int)((blockIdx.x + 1) * rpb), Nr);
  for (int r = blockIdx.x * rpb + sub; r < rend; r += step){
    float v = X[(size_t)r * C + c];
    s += v; s2 += v * v;
  }
  atomicAdd(&stats[c], s);
  atomicAdd(&stats[C + c], s2);
}

// ---------------- batchnorm apply + ELU, in place
__global__ __launch_bounds__(256) void bn_apply(float* __restrict__ X,
    const float* __restrict__ stats, const float* __restrict__ g,
    const float* __restrict__ b, int total, int C, float invN){
  int idx = blockIdx.x * 256 + threadIdx.x;
  if (idx >= total) return;
  int c = idx % C;
  float mean = stats[c] * invN;
  float var = stats[C + c] * invN - mean * mean;
  float inv = rsqrtf(var + 1e-5f);
  float v = (X[idx] - mean) * inv * g[c] + b[c];
  X[idx] = elu(v);
}

// ---------------- global mean pool (accumulate)
__global__ __launch_bounds__(256) void pool_accum(const float* __restrict__ h1,
    const int* __restrict__ batch, float* __restrict__ pool, float* __restrict__ cnt){
  int idx = blockIdx.x * 256 + threadIdx.x;   // < Nn*64
  int n = idx >> 6, c = idx & 63;
  int b = batch[n];
  atomicAdd(&pool[b * 64 + c], h1[idx]);
  if (c == 0) atomicAdd(&cnt[b], 1.0f);
}

// ---------------- classifier stage 1: emb -> z1 (64x256) with BN+ELU; writes emb to d_out
__global__ __launch_bounds__(256) void mlp1(const float* __restrict__ pool,
    const float* __restrict__ cnt, const float* __restrict__ W1,
    const float* __restrict__ b1, const float* __restrict__ g,
    const float* __restrict__ bb, float* __restrict__ z1, float* __restrict__ out_emb){
  __shared__ float emb[64][64];
  int tid = threadIdx.x;
  for (int i = tid; i < 4096; i += 256){
    int b = i >> 6;
    float v = pool[i] / fmaxf(cnt[b], 1.0f);
    emb[b][i & 63] = v;
    out_emb[i] = v;
  }
  __syncthreads();
  int j = tid;  // channel 0..255
  float z[64];
  #pragma unroll
  for (int b = 0; b < 64; b++) z[b] = b1[j];
  for (int k = 0; k < 64; k++){
    float w = W1[k * 256 + j];
    #pragma unroll
    for (int b = 0; b < 64; b++) z[b] += emb[b][k] * w;
  }
  float s = 0.f, s2 = 0.f;
  #pragma unroll
  for (int b = 0; b < 64; b++){ s += z[b]; s2 += z[b] * z[b]; }
  float mean = s * (1.f/64.f);
  float var = s2 * (1.f/64.f) - mean * mean;
  float inv = rsqrtf(var + 1e-5f);
  float sc = g[j] * inv, sh = bb[j] - mean * sc;
  #pragma unroll
  for (int b = 0; b < 64; b++) z1[b * 256 + j] = elu(z[b] * sc + sh);
}

// ---------------- classifier stage 2: z1 -> z2 (64x128) with BN+ELU
__global__ __launch_bounds__(128) void mlp2(const float* __restrict__ z1,
    const float* __restrict__ W2, const float* __restrict__ b2,
    const float* __restrict__ g, const float* __restrict__ bb, float* __restrict__ z2){
  int j = threadIdx.x;  // 0..127
  float acc[64];
  #pragma unroll
  for (int b = 0; b < 64; b++) acc[b] = b2[j];
  for (int k = 0; k < 256; k++){
    float w = W2[k * 128 + j];
    #pragma unroll
    for (int b = 0; b < 64; b++) acc[b] += z1[b * 256 + k] * w;
  }
  float s = 0.f, s2 = 0.f;
  #pragma unroll
  for (int b = 0; b < 64; b++){ s += acc[b]; s2 += acc[b] * acc[b]; }
  float mean = s * (1.f/64.f);
  float var = s2 * (1.f/64.f) - mean * mean;
  float inv = rsqrtf(var + 1e-5f);
  float sc = g[j] * inv, sh = bb[j] - mean * sc;
  #pragma unroll
  for (int b = 0; b < 64; b++) z2[b * 128 + j] = elu(acc[b] * sc + sh);
}

// ---------------- classifier stage 3: logits (64x2)
__global__ __launch_bounds__(128) void mlp3(const float* __restrict__ z2,
    const float* __restrict__ W3, const float* __restrict__ b3, float* __restrict__ out){
  int tid = threadIdx.x;  // 0..127
  int b = tid >> 1, o = tid & 1;
  float acc = b3[o];
  for (int k = 0; k < 128; k++) acc += z2[b * 128 + k] * W3[k * 2 + o];
  out[b * 2 + o] = acc;
}

extern "C" void kernel_launch(void* const* d_in, const int* in_sizes, int n_in,
                              void* d_out, int out_size, void* d_ws, size_t ws_size,
                              hipStream_t stream){
  const float* x      = (const float*)d_in[0];
  const int*   ei     = (const int*)d_in[1];
  const float* ea     = (const float*)d_in[2];
  const int*   batch  = (const int*)d_in[3];
  const float* g0_wl  = (const float*)d_in[4];
  const float* g0_wr  = (const float*)d_in[5];
  const float* g0_we  = (const float*)d_in[6];
  const float* g0_att = (const float*)d_in[7];
  // d_in[8] g0_bias: cancels under BN
  const float* bn0_g  = (const float*)d_in[9];
  const float* bn0_b  = (const float*)d_in[10];
  const float* g1_wl  = (const float*)d_in[11];
  const float* g1_wr  = (const float*)d_in[12];
  const float* g1_we  = (const float*)d_in[13];
  const float* g1_att = (const float*)d_in[14];
  // d_in[15] g1_bias: cancels under BN
  const float* bn1_g  = (const float*)d_in[16];
  const float* bn1_b  = (const float*)d_in[17];
  const float* c_w1   = (const float*)d_in[18];
  const float* c_b1   = (const float*)d_in[19];
  const float* cbn1_g = (const float*)d_in[20];
  const float* cbn1_b = (const float*)d_in[21];
  const float* c_w2   = (const float*)d_in[22];
  const float* c_b2   = (const float*)d_in[23];
  const float* cbn2_g = (const float*)d_in[24];
  const float* cbn2_b = (const float*)d_in[25];
  const float* c_w3   = (const float*)d_in[26];
  const float* c_b3   = (const float*)d_in[27];
  float* out = (float*)d_out;
  float* ws = (float*)d_ws;

  // zero-init accumulators
  hipMemsetAsync(ws + OUT0, 0, 10240000 * sizeof(float), stream);
  hipMemsetAsync(ws + OUT1, 0, 1280000 * sizeof(float), stream);
  hipMemsetAsync(ws + SM, 0, SMALL_CNT * sizeof(float), stream);

  // ---- layer 0 ----
  gemm2<<<dim3(8, 313, 2), 256, 0, stream>>>(x, g0_wl, g0_wr, ws + XL0, ws + XR0,
                                             Nn, 256, 512);
  score_l0<<<Ee / 4, 256, 0, stream>>>(ws + XL0, ws + XR0, ea, g0_we, g0_att, ei,
                                       ws + E0S, (unsigned*)(ws + EMAX0));
  exp_norm<<<Ee * 4 / 256, 256, 0, stream>>>(ws + E0S, (const unsigned*)(ws + EMAX0),
                                             ws + DEN0, ei);
  scatter_l0<<<Ee / 4, 256, 0, stream>>>(ws + XL0, ws + E0S, ws + DEN0, ei, ws + OUT0);
  bn_reduce<<<200, 512, 0, stream>>>(ws + OUT0, ws + BN0S, Nn, 512, 100);
  bn_apply<<<40000, 256, 0, stream>>>(ws + OUT0, ws + BN0S, bn0_g, bn0_b,
                                      Nn * 512, 512, 1.f / Nn);
  // ---- layer 1 ----
  gemm2<<<dim3(4, 313, 2), 256, 0, stream>>>(ws + OUT0, g1_wl, g1_wr, ws + XL1, ws + XR1,
                                             Nn, 512, 256);
  score_l1<<<Ee / 4, 256, 0, stream>>>(ws + XL1, ws + XR1, ea, g1_we, g1_att, ei,
                                       ws + E1S, (unsigned*)(ws + EMAX1));
  exp_norm<<<Ee * 4 / 256, 256, 0, stream>>>(ws + E1S, (const unsigned*)(ws + EMAX1),
                                             ws + DEN1, ei);
  scatter_l1<<<Ee / 4, 256, 0, stream>>>(ws + XL1, ws + E1S, ws + DEN1, ei, ws + OUT1);
  bn_reduce<<<50, 256, 0, stream>>>(ws + OUT1, ws + BN1S, Nn, 64, 400);
  bn_apply<<<5000, 256, 0, stream>>>(ws + OUT1, ws + BN1S, bn1_g, bn1_b,
                                     Nn * 64, 64, 1.f / Nn);
  // ---- pool + classifier ----
  pool_accum<<<Nn * 64 / 256, 256, 0, stream>>>(ws + OUT1, batch, ws + POOLS, ws + CNTS);
  mlp1<<<1, 256, 0, stream>>>(ws + POOLS, ws + CNTS, c_w1, c_b1, cbn1_g, cbn1_b,
                              ws + Z1, out + 128);
  mlp2<<<1, 128, 0, stream>>>(ws + Z1, c_w2, c_b2, cbn2_g, cbn2_b, ws + Z2);
  mlp3<<<1, 128, 0, stream>>>(ws + Z2, c_w3, c_b3, out);
}

// Round 2
// 1396.518 us; speedup vs baseline: 3.9853x; 3.9853x over previous
//
#include <hip/hip_runtime.h>
#include <cmath>

#define Nn 20000
#define Ee 320000

// ---------------- workspace layout (in floats) ----------------
// XL0/XR0 are reused as XL1/XR1 in layer 1 (disjoint lifetimes).
static const size_t XL0  = 0;                    // N*512 (layer1: N*256)
static const size_t XR0  = 10240000;             // N*512 (layer1: N*256)
static const size_t OUT0 = 20480000;             // N*512
static const size_t OUT1 = 30720000;             // N*64
static const size_t ESC  = 32000000;             // E*4 scores (shared by both layers)
static const size_t CSRI = 33280000;             // int region: offs[N+1], cursor[N], eidx[E]
static const size_t SMALL= 33641024;             // zero-init small region
static const size_t BN0S = SMALL;                // 1024
static const size_t BN1S = BN0S + 1024;          // 128
static const size_t POOLS= BN1S + 128;           // 4096
static const size_t CNTS = POOLS + 4096;         // 64
static const size_t ZCNT = (CNTS + 64) - SMALL;  // floats to zero in small region
static const size_t Z1   = CNTS + 64;            // 64*256
static const size_t Z2   = Z1 + 16384;           // 64*128

__device__ __forceinline__ float lrelu(float x){ return x > 0.f ? x : 0.2f * x; }
__device__ __forceinline__ float elu(float x){ return x > 0.f ? x : expm1f(x); }

// ---------------- GEMM: O = A[M,K] @ W[K,Nc]; blockIdx.z picks (Wa->Oa)/(Wb->Ob)
__global__ __launch_bounds__(256) void gemm2(const float* __restrict__ A,
    const float* __restrict__ Wa, const float* __restrict__ Wb,
    float* __restrict__ Oa, float* __restrict__ Ob, int M, int K, int Nc){
  const float* W = blockIdx.z ? Wb : Wa;
  float* O = blockIdx.z ? Ob : Oa;
  __shared__ float As[64][17];   // [m][k], pad
  __shared__ float Ws[16][68];   // [k][n], pad 4 keeps float4 align
  int tid = threadIdx.x;
  int m0 = blockIdx.y * 64, n0 = blockIdx.x * 64;
  int tm = tid >> 4, tn = tid & 15;
  int ar = tid >> 2, ac = (tid & 3) * 4;
  int wr = tid >> 4, wc = (tid & 15) * 4;
  float acc[4][4] = {};
  for (int kt = 0; kt < K; kt += 16){
    float4 av = make_float4(0.f,0.f,0.f,0.f);
    int gr = m0 + ar;
    if (gr < M) av = *(const float4*)&A[(size_t)gr * K + kt + ac];
    As[ar][ac] = av.x; As[ar][ac+1] = av.y; As[ar][ac+2] = av.z; As[ar][ac+3] = av.w;
    float4 wv = *(const float4*)&W[(size_t)(kt + wr) * Nc + n0 + wc];
    *(float4*)&Ws[wr][wc] = wv;
    __syncthreads();
    #pragma unroll
    for (int k = 0; k < 16; k++){
      float a_[4];
      #pragma unroll
      for (int i = 0; i < 4; i++) a_[i] = As[tm*4 + i][k];
      float4 bv = *(float4*)&Ws[k][tn*4];
      float b_[4] = {bv.x, bv.y, bv.z, bv.w};
      #pragma unroll
      for (int i = 0; i < 4; i++)
        #pragma unroll
        for (int j = 0; j < 4; j++)
          acc[i][j] += a_[i] * b_[j];
    }
    __syncthreads();
  }
  #pragma unroll
  for (int i = 0; i < 4; i++){
    int row = m0 + tm*4 + i;
    if (row < M)
      *(float4*)&O[(size_t)row * Nc + n0 + tn*4] =
          make_float4(acc[i][0], acc[i][1], acc[i][2], acc[i][3]);
  }
}

// ---------------- CSR build: histogram / scan / fill ----------------
__global__ __launch_bounds__(256) void csr_hist(const int* __restrict__ ei,
                                                int* __restrict__ cursor){
  int e = blockIdx.x * 256 + threadIdx.x;
  if (e < Ee) atomicAdd(&cursor[ei[Ee + e]], 1);
}

__global__ __launch_bounds__(1024) void csr_scan(int* __restrict__ offs,
                                                 int* __restrict__ cursor){
  __shared__ int part[1024];
  int t = threadIdx.x;
  int base = t * 20;
  int loc[20];
  int s = 0;
  #pragma unroll
  for (int i = 0; i < 20; i++){
    int idx = base + i;
    int v = (idx < Nn) ? cursor[idx] : 0;
    loc[i] = s; s += v;
  }
  part[t] = s;
  __syncthreads();
  for (int off = 1; off < 1024; off <<= 1){
    int v = 0;
    if (t >= off) v = part[t - off];
    __syncthreads();
    if (t >= off) part[t] += v;
    __syncthreads();
  }
  int pre = (t == 0) ? 0 : part[t - 1];
  #pragma unroll
  for (int i = 0; i < 20; i++){
    int idx = base + i;
    if (idx < Nn){ offs[idx] = pre + loc[i]; cursor[idx] = pre + loc[i]; }
  }
  if (t == 1023) offs[Nn] = part[1023];
}

__global__ __launch_bounds__(256) void csr_fill(const int* __restrict__ ei,
    int* __restrict__ cursor, int* __restrict__ eidx){
  int e = blockIdx.x * 256 + threadIdx.x;
  if (e < Ee){
    int d = ei[Ee + e];
    int p = atomicAdd(&cursor[d], 1);
    eidx[p] = e;
  }
}

// ---------------- layer-0 edge scores (512 ch, H=4,C=128), wave per edge
__global__ __launch_bounds__(256) void score_l0(const float* __restrict__ xl,
    const float* __restrict__ xr, const float* __restrict__ ea,
    const float* __restrict__ we, const float* __restrict__ att,
    const int* __restrict__ ei, float* __restrict__ esc){
  int eid = blockIdx.x * 4 + (threadIdx.x >> 6);
  int lane = threadIdx.x & 63;
  int src = ei[eid], dst = ei[Ee + eid];
  float a = ea[eid];
  int c = lane << 3;                       // 8 channels per lane
  const float4* lp = (const float4*)&xl[(size_t)src * 512 + c];
  const float4* rp = (const float4*)&xr[(size_t)dst * 512 + c];
  const float4* wp = (const float4*)&we[c];
  const float4* tp = (const float4*)&att[c];
  float p = 0.f;
  #pragma unroll
  for (int q = 0; q < 2; q++){
    float4 l = lp[q], r = rp[q], w = wp[q], t = tp[q];
    p += lrelu(l.x + r.x + a * w.x) * t.x;
    p += lrelu(l.y + r.y + a * w.y) * t.y;
    p += lrelu(l.z + r.z + a * w.z) * t.z;
    p += lrelu(l.w + r.w + a * w.w) * t.w;
  }
  p += __shfl_xor(p, 8); p += __shfl_xor(p, 4);
  p += __shfl_xor(p, 2); p += __shfl_xor(p, 1);
  if ((lane & 15) == 0) esc[eid * 4 + (lane >> 4)] = p;
}

// ---------------- layer-1 edge scores (256 ch, H=4,C=64)
__global__ __launch_bounds__(256) void score_l1(const float* __restrict__ xl,
    const float* __restrict__ xr, const float* __restrict__ ea,
    const float* __restrict__ we, const float* __restrict__ att,
    const int* __restrict__ ei, float* __restrict__ esc){
  int eid = blockIdx.x * 4 + (threadIdx.x >> 6);
  int lane = threadIdx.x & 63;
  int src = ei[eid], dst = ei[Ee + eid];
  float a = ea[eid];
  int c = lane << 2;                       // 4 channels per lane
  float4 l = *(const float4*)&xl[(size_t)src * 256 + c];
  float4 r = *(const float4*)&xr[(size_t)dst * 256 + c];
  float4 w = *(const float4*)&we[c];
  float4 t = *(const float4*)&att[c];
  float p = 0.f;
  p += lrelu(l.x + r.x + a * w.x) * t.x;
  p += lrelu(l.y + r.y + a * w.y) * t.y;
  p += lrelu(l.z + r.z + a * w.z) * t.z;
  p += lrelu(l.w + r.w + a * w.w) * t.w;
  p += __shfl_xor(p, 8); p += __shfl_xor(p, 4);
  p += __shfl_xor(p, 2); p += __shfl_xor(p, 1);
  if ((lane & 15) == 0) esc[eid * 4 + (lane >> 4)] = p;
}

// ---------------- per-dst softmax over incoming edges; alpha written in place
__global__ __launch_bounds__(256) void softmax_dst(float* __restrict__ esc,
    const int* __restrict__ offs, const int* __restrict__ eidx){
  int idx = blockIdx.x * 256 + threadIdx.x;   // (dst, head)
  if (idx >= Nn * 4) return;
  int n = idx >> 2, h = idx & 3;
  int s = offs[n], e = offs[n + 1];
  if (s == e) return;
  float m = -INFINITY;
  for (int i = s; i < e; i++) m = fmaxf(m, esc[eidx[i] * 4 + h]);
  float den = 0.f;
  for (int i = s; i < e; i++){
    int id = eidx[i] * 4 + h;
    float v = expf(esc[id] - m);
    esc[id] = v; den += v;
  }
  float inv = 1.f / (den + 1e-16f);
  for (int i = s; i < e; i++) esc[eidx[i] * 4 + h] *= inv;
}

// ---------------- layer-0 aggregation: wave per dst, no atomics
__global__ __launch_bounds__(256) void aggregate_l0(const float* __restrict__ xl,
    const float* __restrict__ esc, const int* __restrict__ ei,
    const int* __restrict__ offs, const int* __restrict__ eidx,
    float* __restrict__ out){
  int n = blockIdx.x * 4 + (threadIdx.x >> 6);
  int lane = threadIdx.x & 63;
  int s = offs[n], e = offs[n + 1];
  int c = lane << 3;          // 8 channels/lane
  int h = lane >> 4;          // head = c/128
  float4 a0 = make_float4(0.f,0.f,0.f,0.f), a1 = a0;
  for (int i = s; i < e; i++){
    int eid = eidx[i];
    float alpha = esc[eid * 4 + h];
    int src = ei[eid];
    const float4* lp = (const float4*)&xl[(size_t)src * 512 + c];
    float4 v0 = lp[0], v1 = lp[1];
    a0.x += alpha * v0.x; a0.y += alpha * v0.y;
    a0.z += alpha * v0.z; a0.w += alpha * v0.w;
    a1.x += alpha * v1.x; a1.y += alpha * v1.y;
    a1.z += alpha * v1.z; a1.w += alpha * v1.w;
  }
  float4* op = (float4*)&out[(size_t)n * 512 + c];
  op[0] = a0; op[1] = a1;
}

// ---------------- layer-1 aggregation with head-mean folded in
__global__ __launch_bounds__(256) void aggregate_l1(const float* __restrict__ xl,
    const float* __restrict__ esc, const int* __restrict__ ei,
    const int* __restrict__ offs, const int* __restrict__ eidx,
    float* __restrict__ out){
  int n = blockIdx.x * 4 + (threadIdx.x >> 6);
  int lane = threadIdx.x & 63;                // output channel
  int s = offs[n], e = offs[n + 1];
  float acc = 0.f;
  for (int i = s; i < e; i++){
    int eid = eidx[i];
    int src = ei[eid];
    const float* xp = &xl[(size_t)src * 256 + lane];
    #pragma unroll
    for (int h = 0; h < 4; h++)
      acc += esc[eid * 4 + h] * 0.25f * xp[h * 64];
  }
  out[(size_t)n * 64 + lane] = acc;
}

// ---------------- batchnorm reduce: stats[c]=sum, stats[C+c]=sumsq
__global__ void bn_reduce(const float* __restrict__ X, float* __restrict__ stats,
                          int Nr, int C, int rpb){
  int tid = threadIdx.x;
  int c = tid % C, sub = tid / C, step = blockDim.x / C;
  float s = 0.f, s2 = 0.f;
  int rend = min((int)((blockIdx.x + 1) * rpb), Nr);
  for (int r = blockIdx.x * rpb + sub; r < rend; r += step){
    float v = X[(size_t)r * C + c];
    s += v; s2 += v * v;
  }
  atomicAdd(&stats[c], s);
  atomicAdd(&stats[C + c], s2);
}

// ---------------- batchnorm apply + ELU, in place
__global__ __launch_bounds__(256) void bn_apply(float* __restrict__ X,
    const float* __restrict__ stats, const float* __restrict__ g,
    const float* __restrict__ b, int total, int C, float invN){
  int idx = blockIdx.x * 256 + threadIdx.x;
  if (idx >= total) return;
  int c = idx % C;
  float mean = stats[c] * invN;
  float var = stats[C + c] * invN - mean * mean;
  float inv = rsqrtf(var + 1e-5f);
  float v = (X[idx] - mean) * inv * g[c] + b[c];
  X[idx] = elu(v);
}

// ---------------- global mean pool (accumulate)
__global__ __launch_bounds__(256) void pool_accum(const float* __restrict__ h1,
    const int* __restrict__ batch, float* __restrict__ pool, float* __restrict__ cnt){
  int idx = blockIdx.x * 256 + threadIdx.x;   // < Nn*64
  int n = idx >> 6, c = idx & 63;
  int b = batch[n];
  atomicAdd(&pool[b * 64 + c], h1[idx]);
  if (c == 0) atomicAdd(&cnt[b], 1.0f);
}

// ---------------- classifier stage 1
__global__ __launch_bounds__(256) void mlp1(const float* __restrict__ pool,
    const float* __restrict__ cnt, const float* __restrict__ W1,
    const float* __restrict__ b1, const float* __restrict__ g,
    const float* __restrict__ bb, float* __restrict__ z1, float* __restrict__ out_emb){
  __shared__ float emb[64][64];
  int tid = threadIdx.x;
  for (int i = tid; i < 4096; i += 256){
    int b = i >> 6;
    float v = pool[i] / fmaxf(cnt[b], 1.0f);
    emb[b][i & 63] = v;
    out_emb[i] = v;
  }
  __syncthreads();
  int j = tid;
  float z[64];
  #pragma unroll
  for (int b = 0; b < 64; b++) z[b] = b1[j];
  for (int k = 0; k < 64; k++){
    float w = W1[k * 256 + j];
    #pragma unroll
    for (int b = 0; b < 64; b++) z[b] += emb[b][k] * w;
  }
  float s = 0.f, s2 = 0.f;
  #pragma unroll
  for (int b = 0; b < 64; b++){ s += z[b]; s2 += z[b] * z[b]; }
  float mean = s * (1.f/64.f);
  float var = s2 * (1.f/64.f) - mean * mean;
  float inv = rsqrtf(var + 1e-5f);
  float sc = g[j] * inv, sh = bb[j] - mean * sc;
  #pragma unroll
  for (int b = 0; b < 64; b++) z1[b * 256 + j] = elu(z[b] * sc + sh);
}

// ---------------- classifier stage 2
__global__ __launch_bounds__(128) void mlp2(const float* __restrict__ z1,
    const float* __restrict__ W2, const float* __restrict__ b2,
    const float* __restrict__ g, const float* __restrict__ bb, float* __restrict__ z2){
  int j = threadIdx.x;
  float acc[64];
  #pragma unroll
  for (int b = 0; b < 64; b++) acc[b] = b2[j];
  for (int k = 0; k < 256; k++){
    float w = W2[k * 128 + j];
    #pragma unroll
    for (int b = 0; b < 64; b++) acc[b] += z1[b * 256 + k] * w;
  }
  float s = 0.f, s2 = 0.f;
  #pragma unroll
  for (int b = 0; b < 64; b++){ s += acc[b]; s2 += acc[b] * acc[b]; }
  float mean = s * (1.f/64.f);
  float var = s2 * (1.f/64.f) - mean * mean;
  float inv = rsqrtf(var + 1e-5f);
  float sc = g[j] * inv, sh = bb[j] - mean * sc;
  #pragma unroll
  for (int b = 0; b < 64; b++) z2[b * 128 + j] = elu(acc[b] * sc + sh);
}

// ---------------- classifier stage 3
__global__ __launch_bounds__(128) void mlp3(const float* __restrict__ z2,
    const float* __restrict__ W3, const float* __restrict__ b3, float* __restrict__ out){
  int tid = threadIdx.x;
  int b = tid >> 1, o = tid & 1;
  float acc = b3[o];
  for (int k = 0; k < 128; k++) acc += z2[b * 128 + k] * W3[k * 2 + o];
  out[b * 2 + o] = acc;
}

extern "C" void kernel_launch(void* const* d_in, const int* in_sizes, int n_in,
                              void* d_out, int out_size, void* d_ws, size_t ws_size,
                              hipStream_t stream){
  const float* x      = (const float*)d_in[0];
  const int*   ei     = (const int*)d_in[1];
  const float* ea     = (const float*)d_in[2];
  const int*   batch  = (const int*)d_in[3];
  const float* g0_wl  = (const float*)d_in[4];
  const float* g0_wr  = (const float*)d_in[5];
  const float* g0_we  = (const float*)d_in[6];
  const float* g0_att = (const float*)d_in[7];
  const float* bn0_g  = (const float*)d_in[9];
  const float* bn0_b  = (const float*)d_in[10];
  const float* g1_wl  = (const float*)d_in[11];
  const float* g1_wr  = (const float*)d_in[12];
  const float* g1_we  = (const float*)d_in[13];
  const float* g1_att = (const float*)d_in[14];
  const float* bn1_g  = (const float*)d_in[16];
  const float* bn1_b  = (const float*)d_in[17];
  const float* c_w1   = (const float*)d_in[18];
  const float* c_b1   = (const float*)d_in[19];
  const float* cbn1_g = (const float*)d_in[20];
  const float* cbn1_b = (const float*)d_in[21];
  const float* c_w2   = (const float*)d_in[22];
  const float* c_b2   = (const float*)d_in[23];
  const float* cbn2_g = (const float*)d_in[24];
  const float* cbn2_b = (const float*)d_in[25];
  const float* c_w3   = (const float*)d_in[26];
  const float* c_b3   = (const float*)d_in[27];
  float* out = (float*)d_out;
  float* ws = (float*)d_ws;

  int* offs   = (int*)(ws + CSRI);          // N+1
  int* cursor = offs + (Nn + 1);            // N
  int* eidx   = cursor + Nn;                // E

  // zero: cursor (histogram) + small accumulators
  hipMemsetAsync(cursor, 0, Nn * sizeof(int), stream);
  hipMemsetAsync(ws + SMALL, 0, ZCNT * sizeof(float), stream);

  // ---- CSR by destination (shared by both layers) ----
  csr_hist<<<(Ee + 255) / 256, 256, 0, stream>>>(ei, cursor);
  csr_scan<<<1, 1024, 0, stream>>>(offs, cursor);
  csr_fill<<<(Ee + 255) / 256, 256, 0, stream>>>(ei, cursor, eidx);

  // ---- layer 0 ----
  gemm2<<<dim3(8, 313, 2), 256, 0, stream>>>(x, g0_wl, g0_wr, ws + XL0, ws + XR0,
                                             Nn, 256, 512);
  score_l0<<<Ee / 4, 256, 0, stream>>>(ws + XL0, ws + XR0, ea, g0_we, g0_att, ei,
                                       ws + ESC);
  softmax_dst<<<(Nn * 4 + 255) / 256, 256, 0, stream>>>(ws + ESC, offs, eidx);
  aggregate_l0<<<Nn / 4, 256, 0, stream>>>(ws + XL0, ws + ESC, ei, offs, eidx,
                                           ws + OUT0);
  bn_reduce<<<200, 512, 0, stream>>>(ws + OUT0, ws + BN0S, Nn, 512, 100);
  bn_apply<<<40000, 256, 0, stream>>>(ws + OUT0, ws + BN0S, bn0_g, bn0_b,
                                      Nn * 512, 512, 1.f / Nn);
  // ---- layer 1 (XL1/XR1 alias XL0/XR0) ----
  gemm2<<<dim3(4, 313, 2), 256, 0, stream>>>(ws + OUT0, g1_wl, g1_wr, ws + XL0, ws + XR0,
                                             Nn, 512, 256);
  score_l1<<<Ee / 4, 256, 0, stream>>>(ws + XL0, ws + XR0, ea, g1_we, g1_att, ei,
                                       ws + ESC);
  softmax_dst<<<(Nn * 4 + 255) / 256, 256, 0, stream>>>(ws + ESC, offs, eidx);
  aggregate_l1<<<Nn / 4, 256, 0, stream>>>(ws + XL0, ws + ESC, ei, offs, eidx,
                                           ws + OUT1);
  bn_reduce<<<50, 256, 0, stream>>>(ws + OUT1, ws + BN1S, Nn, 64, 400);
  bn_apply<<<5000, 256, 0, stream>>>(ws + OUT1, ws + BN1S, bn1_g, bn1_b,
                                     Nn * 64, 64, 1.f / Nn);
  // ---- pool + classifier ----
  pool_accum<<<Nn * 64 / 256, 256, 0, stream>>>(ws + OUT1, batch, ws + POOLS, ws + CNTS);
  mlp1<<<1, 256, 0, stream>>>(ws + POOLS, ws + CNTS, c_w1, c_b1, cbn1_g, cbn1_b,
                              ws + Z1, out + 128);
  mlp2<<<1, 128, 0, stream>>>(ws + Z1, c_w2, c_b2, cbn2_g, cbn2_b, ws + Z2);
  mlp3<<<1, 128, 0, stream>>>(ws + Z2, c_w3, c_b3, out);
}

// Round 3
// 1003.332 us; speedup vs baseline: 5.5471x; 1.3919x over previous
//
#include <hip/hip_runtime.h>
#include <cmath>

#define Nn 20000
#define Ee 320000

typedef unsigned short u16;
typedef __bf16 bf16x8 __attribute__((ext_vector_type(8)));
typedef float f32x4 __attribute__((ext_vector_type(4)));

// ---------------- workspace layout (float units) ----------------
static const size_t OUT0 = 0;                    // N*512 fp32
static const size_t XL0B = 10240000;             // N*512 bf16 (layer1 reuses as N*256)
static const size_t XR0B = 15360000;             // N*512 bf16
static const size_t H0B  = 20480000;             // N*512 bf16 (post-BN h0)
static const size_t XB   = 25600000;             // N*256 bf16
static const size_t WTS  = 28160000;             // 4 x 131072 u16 (transposed bf16 weights)
static const size_t OUT1 = 28422144;             // N*64 fp32
static const size_t ESC  = 29702144;             // E*4 fp32
static const size_t CSRI = 30982144;             // ints: offs[N+1], cursor[N], eidx[E]
static const size_t SMALL= 31342208;
static const size_t BN0S = SMALL;                // 1024
static const size_t BN1S = BN0S + 1024;          // 128
static const size_t POOLS= BN1S + 128;           // 4096
static const size_t CNTS = POOLS + 4096;         // 64
static const size_t ZCNT = (CNTS + 64) - SMALL;
static const size_t Z1   = CNTS + 64;            // 64*256
static const size_t Z2   = Z1 + 16384;           // 64*128

__device__ __forceinline__ float lrelu(float x){ return x > 0.f ? x : 0.2f * x; }
__device__ __forceinline__ float elu(float x){ return x > 0.f ? x : expm1f(x); }
__device__ __forceinline__ u16 fbf(float f){           // fp32 -> bf16 RNE
  unsigned u = __float_as_uint(f);
  return (u16)((u + 0x7fffu + ((u >> 16) & 1u)) >> 16);
}
__device__ __forceinline__ float blo(unsigned u){ return __uint_as_float(u << 16); }
__device__ __forceinline__ float bhi(unsigned u){ return __uint_as_float(u & 0xffff0000u); }
__device__ __forceinline__ float b2f(u16 v){ return __uint_as_float(((unsigned)v) << 16); }

// ---------------- fp32 -> bf16 (n multiple of 4) ----------------
__global__ __launch_bounds__(256) void conv_bf(const float* __restrict__ src,
                                               u16* __restrict__ dst, int n4){
  int i = blockIdx.x * 256 + threadIdx.x;
  if (i < n4){
    float4 v = ((const float4*)src)[i];
    ushort4 o; o.x = fbf(v.x); o.y = fbf(v.y); o.z = fbf(v.z); o.w = fbf(v.w);
    ((ushort4*)dst)[i] = o;
  }
}

// ---------------- W[K][N] fp32 -> WT[N][K] bf16 ----------------
__global__ __launch_bounds__(256) void conv_wt(const float* __restrict__ W,
                                               u16* __restrict__ WT, int K, int N){
  int i = blockIdx.x * 256 + threadIdx.x;
  if (i < K * N){
    int n = i / K, k = i - n * K;
    WT[i] = fbf(W[k * N + n]);
  }
}

// ---------------- MFMA GEMM: O[M][Nc] = A[M][K] @ WT[Nc][K]^T, all bf16, fp32 acc
// 128x128 tile, BK=32, 4 waves each 64x64 (4x4 frags of 16x16x32). z picks a/b.
__global__ __launch_bounds__(256) void gemm_mfma(const u16* __restrict__ A,
    const u16* __restrict__ WTa, const u16* __restrict__ WTb,
    u16* __restrict__ Oa, u16* __restrict__ Ob, int M, int K, int Nc){
  const u16* WT = blockIdx.z ? WTb : WTa;
  u16* O = blockIdx.z ? Ob : Oa;
  __shared__ u16 As[128 * 40];   // row stride 40 u16 = 80B -> 2-way bank alias (free)
  __shared__ u16 Bs[128 * 40];
  int tid = threadIdx.x;
  int m0 = blockIdx.y * 128, n0 = blockIdx.x * 128;
  int lane = tid & 63, w = tid >> 6;
  int wr = (w >> 1) * 64, wc = (w & 1) * 64;
  int l16 = lane & 15, kq = lane >> 4;
  f32x4 acc[4][4] = {};
  int srow = tid >> 2, scol = (tid & 3) * 8;   // 4 threads x 16B per 64B k-row
  for (int kt = 0; kt < K; kt += 32){
    #pragma unroll
    for (int r = 0; r < 2; r++){
      int row = r * 64 + srow;
      uint4 av = make_uint4(0u, 0u, 0u, 0u);
      int gr = m0 + row;
      if (gr < M) av = *(const uint4*)&A[(size_t)gr * K + kt + scol];
      *(uint4*)&As[row * 40 + scol] = av;
      uint4 bv = *(const uint4*)&WT[(size_t)(n0 + row) * K + kt + scol];
      *(uint4*)&Bs[row * 40 + scol] = bv;
    }
    __syncthreads();
    bf16x8 af[4], bfr[4];
    #pragma unroll
    for (int i = 0; i < 4; i++){
      af[i]  = *(bf16x8*)&As[(wr + i * 16 + l16) * 40 + kq * 8];
      bfr[i] = *(bf16x8*)&Bs[(wc + i * 16 + l16) * 40 + kq * 8];
    }
    #pragma unroll
    for (int i = 0; i < 4; i++)
      #pragma unroll
      for (int j = 0; j < 4; j++)
        acc[i][j] = __builtin_amdgcn_mfma_f32_16x16x32_bf16(af[i], bfr[j], acc[i][j], 0, 0, 0);
    __syncthreads();
  }
  // C/D layout: col = lane&15, row = (lane>>4)*4 + reg  [m89]
  #pragma unroll
  for (int i = 0; i < 4; i++){
    #pragma unroll
    for (int rg = 0; rg < 4; rg++){
      int row = m0 + wr + i * 16 + kq * 4 + rg;
      if (row < M){
        #pragma unroll
        for (int j = 0; j < 4; j++){
          int col = n0 + wc + j * 16 + l16;
          O[(size_t)row * Nc + col] = fbf(acc[i][j][rg]);
        }
      }
    }
  }
}

// ---------------- CSR build ----------------
__global__ __launch_bounds__(256) void csr_hist(const int* __restrict__ ei,
                                                int* __restrict__ cursor){
  int e = blockIdx.x * 256 + threadIdx.x;
  if (e < Ee) atomicAdd(&cursor[ei[Ee + e]], 1);
}

__global__ __launch_bounds__(1024) void csr_scan(int* __restrict__ offs,
                                                 int* __restrict__ cursor){
  __shared__ int part[1024];
  int t = threadIdx.x;
  int base = t * 20;
  int loc[20];
  int s = 0;
  #pragma unroll
  for (int i = 0; i < 20; i++){
    int idx = base + i;
    int v = (idx < Nn) ? cursor[idx] : 0;
    loc[i] = s; s += v;
  }
  part[t] = s;
  __syncthreads();
  for (int off = 1; off < 1024; off <<= 1){
    int v = 0;
    if (t >= off) v = part[t - off];
    __syncthreads();
    if (t >= off) part[t] += v;
    __syncthreads();
  }
  int pre = (t == 0) ? 0 : part[t - 1];
  #pragma unroll
  for (int i = 0; i < 20; i++){
    int idx = base + i;
    if (idx < Nn){ offs[idx] = pre + loc[i]; cursor[idx] = pre + loc[i]; }
  }
  if (t == 1023) offs[Nn] = part[1023];
}

__global__ __launch_bounds__(256) void csr_fill(const int* __restrict__ ei,
    int* __restrict__ cursor, int* __restrict__ eidx){
  int e = blockIdx.x * 256 + threadIdx.x;
  if (e < Ee){
    int d = ei[Ee + e];
    int p = atomicAdd(&cursor[d], 1);
    eidx[p] = e;
  }
}

// ---------------- layer-0 edge scores (bf16 xl/xr, 512 ch), wave/edge
__global__ __launch_bounds__(256) void score_l0(const u16* __restrict__ xl,
    const u16* __restrict__ xr, const float* __restrict__ ea,
    const float* __restrict__ we, const float* __restrict__ att,
    const int* __restrict__ ei, float* __restrict__ esc){
  int eid = blockIdx.x * 4 + (threadIdx.x >> 6);
  int lane = threadIdx.x & 63;
  int src = ei[eid], dst = ei[Ee + eid];
  float a = ea[eid];
  int c = lane << 3;
  uint4 lu = *(const uint4*)&xl[(size_t)src * 512 + c];
  uint4 ru = *(const uint4*)&xr[(size_t)dst * 512 + c];
  float4 w0 = *(const float4*)&we[c],  w1 = *(const float4*)&we[c + 4];
  float4 t0 = *(const float4*)&att[c], t1 = *(const float4*)&att[c + 4];
  float p = 0.f;
  p += lrelu(blo(lu.x) + blo(ru.x) + a * w0.x) * t0.x;
  p += lrelu(bhi(lu.x) + bhi(ru.x) + a * w0.y) * t0.y;
  p += lrelu(blo(lu.y) + blo(ru.y) + a * w0.z) * t0.z;
  p += lrelu(bhi(lu.y) + bhi(ru.y) + a * w0.w) * t0.w;
  p += lrelu(blo(lu.z) + blo(ru.z) + a * w1.x) * t1.x;
  p += lrelu(bhi(lu.z) + bhi(ru.z) + a * w1.y) * t1.y;
  p += lrelu(blo(lu.w) + blo(ru.w) + a * w1.z) * t1.z;
  p += lrelu(bhi(lu.w) + bhi(ru.w) + a * w1.w) * t1.w;
  p += __shfl_xor(p, 8); p += __shfl_xor(p, 4);
  p += __shfl_xor(p, 2); p += __shfl_xor(p, 1);
  if ((lane & 15) == 0) esc[eid * 4 + (lane >> 4)] = p;
}

// ---------------- layer-1 edge scores (bf16, 256 ch)
__global__ __launch_bounds__(256) void score_l1(const u16* __restrict__ xl,
    const u16* __restrict__ xr, const float* __restrict__ ea,
    const float* __restrict__ we, const float* __restrict__ att,
    const int* __restrict__ ei, float* __restrict__ esc){
  int eid = blockIdx.x * 4 + (threadIdx.x >> 6);
  int lane = threadIdx.x & 63;
  int src = ei[eid], dst = ei[Ee + eid];
  float a = ea[eid];
  int c = lane << 2;
  uint2 lu = *(const uint2*)&xl[(size_t)src * 256 + c];
  uint2 ru = *(const uint2*)&xr[(size_t)dst * 256 + c];
  float4 w = *(const float4*)&we[c];
  float4 t = *(const float4*)&att[c];
  float p = 0.f;
  p += lrelu(blo(lu.x) + blo(ru.x) + a * w.x) * t.x;
  p += lrelu(bhi(lu.x) + bhi(ru.x) + a * w.y) * t.y;
  p += lrelu(blo(lu.y) + blo(ru.y) + a * w.z) * t.z;
  p += lrelu(bhi(lu.y) + bhi(ru.y) + a * w.w) * t.w;
  p += __shfl_xor(p, 8); p += __shfl_xor(p, 4);
  p += __shfl_xor(p, 2); p += __shfl_xor(p, 1);
  if ((lane & 15) == 0) esc[eid * 4 + (lane >> 4)] = p;
}

// ---------------- per-dst softmax over incoming edges
__global__ __launch_bounds__(256) void softmax_dst(float* __restrict__ esc,
    const int* __restrict__ offs, const int* __restrict__ eidx){
  int idx = blockIdx.x * 256 + threadIdx.x;
  if (idx >= Nn * 4) return;
  int n = idx >> 2, h = idx & 3;
  int s = offs[n], e = offs[n + 1];
  if (s == e) return;
  float m = -INFINITY;
  for (int i = s; i < e; i++) m = fmaxf(m, esc[eidx[i] * 4 + h]);
  float den = 0.f;
  for (int i = s; i < e; i++){
    int id = eidx[i] * 4 + h;
    float v = expf(esc[id] - m);
    esc[id] = v; den += v;
  }
  float inv = 1.f / (den + 1e-16f);
  for (int i = s; i < e; i++) esc[eidx[i] * 4 + h] *= inv;
}

// ---------------- layer-0 aggregation (bf16 gather, fp32 out), wave/dst
__global__ __launch_bounds__(256) void aggregate_l0(const u16* __restrict__ xl,
    const float* __restrict__ esc, const int* __restrict__ ei,
    const int* __restrict__ offs, const int* __restrict__ eidx,
    float* __restrict__ out){
  int n = blockIdx.x * 4 + (threadIdx.x >> 6);
  int lane = threadIdx.x & 63;
  int s = offs[n], e = offs[n + 1];
  int c = lane << 3, h = lane >> 4;
  float a0=0.f,a1=0.f,a2=0.f,a3=0.f,a4=0.f,a5=0.f,a6=0.f,a7=0.f;
  for (int i = s; i < e; i++){
    int eid = eidx[i];
    float alpha = esc[eid * 4 + h];
    int src = ei[eid];
    uint4 v = *(const uint4*)&xl[(size_t)src * 512 + c];
    a0 += alpha * blo(v.x); a1 += alpha * bhi(v.x);
    a2 += alpha * blo(v.y); a3 += alpha * bhi(v.y);
    a4 += alpha * blo(v.z); a5 += alpha * bhi(v.z);
    a6 += alpha * blo(v.w); a7 += alpha * bhi(v.w);
  }
  float4* op = (float4*)&out[(size_t)n * 512 + c];
  op[0] = make_float4(a0, a1, a2, a3);
  op[1] = make_float4(a4, a5, a6, a7);
}

// ---------------- layer-1 aggregation, head-mean folded, wave/dst
__global__ __launch_bounds__(256) void aggregate_l1(const u16* __restrict__ xl,
    const float* __restrict__ esc, const int* __restrict__ ei,
    const int* __restrict__ offs, const int* __restrict__ eidx,
    float* __restrict__ out){
  int n = blockIdx.x * 4 + (threadIdx.x >> 6);
  int lane = threadIdx.x & 63;   // output channel
  int s = offs[n], e = offs[n + 1];
  float acc = 0.f;
  for (int i = s; i < e; i++){
    int eid = eidx[i];
    int src = ei[eid];
    float4 al = *(const float4*)&esc[eid * 4];
    const u16* xp = &xl[(size_t)src * 256 + lane];
    acc += al.x * 0.25f * b2f(xp[0]);
    acc += al.y * 0.25f * b2f(xp[64]);
    acc += al.z * 0.25f * b2f(xp[128]);
    acc += al.w * 0.25f * b2f(xp[192]);
  }
  out[(size_t)n * 64 + lane] = acc;
}

// ---------------- batchnorm reduce
__global__ void bn_reduce(const float* __restrict__ X, float* __restrict__ stats,
                          int Nr, int C, int rpb){
  int tid = threadIdx.x;
  int c = tid % C, sub = tid / C, step = blockDim.x / C;
  float s = 0.f, s2 = 0.f;
  int rend = min((int)((blockIdx.x + 1) * rpb), Nr);
  for (int r = blockIdx.x * rpb + sub; r < rend; r += step){
    float v = X[(size_t)r * C + c];
    s += v; s2 += v * v;
  }
  atomicAdd(&stats[c], s);
  atomicAdd(&stats[C + c], s2);
}

// ---------------- BN+ELU -> bf16 out (layer 0 path feeds MFMA GEMM)
__global__ __launch_bounds__(256) void bn_apply_bf(const float* __restrict__ X,
    const float* __restrict__ stats, const float* __restrict__ g,
    const float* __restrict__ b, u16* __restrict__ Xb, int total, int C, float invN){
  int idx = blockIdx.x * 256 + threadIdx.x;
  if (idx >= total) return;
  int c = idx % C;
  float mean = stats[c] * invN;
  float var = stats[C + c] * invN - mean * mean;
  float inv = rsqrtf(var + 1e-5f);
  float v = (X[idx] - mean) * inv * g[c] + b[c];
  Xb[idx] = fbf(elu(v));
}

// ---------------- BN+ELU fp32 in place (layer 1 path)
__global__ __launch_bounds__(256) void bn_apply(float* __restrict__ X,
    const float* __restrict__ stats, const float* __restrict__ g,
    const float* __restrict__ b, int total, int C, float invN){
  int idx = blockIdx.x * 256 + threadIdx.x;
  if (idx >= total) return;
  int c = idx % C;
  float mean = stats[c] * invN;
  float var = stats[C + c] * invN - mean * mean;
  float inv = rsqrtf(var + 1e-5f);
  float v = (X[idx] - mean) * inv * g[c] + b[c];
  X[idx] = elu(v);
}

// ---------------- global mean pool
__global__ __launch_bounds__(256) void pool_accum(const float* __restrict__ h1,
    const int* __restrict__ batch, float* __restrict__ pool, float* __restrict__ cnt){
  int idx = blockIdx.x * 256 + threadIdx.x;
  int n = idx >> 6, c = idx & 63;
  int b = batch[n];
  atomicAdd(&pool[b * 64 + c], h1[idx]);
  if (c == 0) atomicAdd(&cnt[b], 1.0f);
}

// ---------------- classifier ----------------
__global__ __launch_bounds__(256) void mlp1(const float* __restrict__ pool,
    const float* __restrict__ cnt, const float* __restrict__ W1,
    const float* __restrict__ b1, const float* __restrict__ g,
    const float* __restrict__ bb, float* __restrict__ z1, float* __restrict__ out_emb){
  __shared__ float emb[64][64];
  int tid = threadIdx.x;
  for (int i = tid; i < 4096; i += 256){
    int b = i >> 6;
    float v = pool[i] / fmaxf(cnt[b], 1.0f);
    emb[b][i & 63] = v;
    out_emb[i] = v;
  }
  __syncthreads();
  int j = tid;
  float z[64];
  #pragma unroll
  for (int b = 0; b < 64; b++) z[b] = b1[j];
  for (int k = 0; k < 64; k++){
    float w = W1[k * 256 + j];
    #pragma unroll
    for (int b = 0; b < 64; b++) z[b] += emb[b][k] * w;
  }
  float s = 0.f, s2 = 0.f;
  #pragma unroll
  for (int b = 0; b < 64; b++){ s += z[b]; s2 += z[b] * z[b]; }
  float mean = s * (1.f/64.f);
  float var = s2 * (1.f/64.f) - mean * mean;
  float inv = rsqrtf(var + 1e-5f);
  float sc = g[j] * inv, sh = bb[j] - mean * sc;
  #pragma unroll
  for (int b = 0; b < 64; b++) z1[b * 256 + j] = elu(z[b] * sc + sh);
}

__global__ __launch_bounds__(128) void mlp2(const float* __restrict__ z1,
    const float* __restrict__ W2, const float* __restrict__ b2,
    const float* __restrict__ g, const float* __restrict__ bb, float* __restrict__ z2){
  int j = threadIdx.x;
  float acc[64];
  #pragma unroll
  for (int b = 0; b < 64; b++) acc[b] = b2[j];
  for (int k = 0; k < 256; k++){
    float w = W2[k * 128 + j];
    #pragma unroll
    for (int b = 0; b < 64; b++) acc[b] += z1[b * 256 + k] * w;
  }
  float s = 0.f, s2 = 0.f;
  #pragma unroll
  for (int b = 0; b < 64; b++){ s += acc[b]; s2 += acc[b] * acc[b]; }
  float mean = s * (1.f/64.f);
  float var = s2 * (1.f/64.f) - mean * mean;
  float inv = rsqrtf(var + 1e-5f);
  float sc = g[j] * inv, sh = bb[j] - mean * sc;
  #pragma unroll
  for (int b = 0; b < 64; b++) z2[b * 128 + j] = elu(acc[b] * sc + sh);
}

__global__ __launch_bounds__(128) void mlp3(const float* __restrict__ z2,
    const float* __restrict__ W3, const float* __restrict__ b3, float* __restrict__ out){
  int tid = threadIdx.x;
  int b = tid >> 1, o = tid & 1;
  float acc = b3[o];
  for (int k = 0; k < 128; k++) acc += z2[b * 128 + k] * W3[k * 2 + o];
  out[b * 2 + o] = acc;
}

extern "C" void kernel_launch(void* const* d_in, const int* in_sizes, int n_in,
                              void* d_out, int out_size, void* d_ws, size_t ws_size,
                              hipStream_t stream){
  const float* x      = (const float*)d_in[0];
  const int*   ei     = (const int*)d_in[1];
  const float* ea     = (const float*)d_in[2];
  const int*   batch  = (const int*)d_in[3];
  const float* g0_wl  = (const float*)d_in[4];
  const float* g0_wr  = (const float*)d_in[5];
  const float* g0_we  = (const float*)d_in[6];
  const float* g0_att = (const float*)d_in[7];
  const float* bn0_g  = (const float*)d_in[9];
  const float* bn0_b  = (const float*)d_in[10];
  const float* g1_wl  = (const float*)d_in[11];
  const float* g1_wr  = (const float*)d_in[12];
  const float* g1_we  = (const float*)d_in[13];
  const float* g1_att = (const float*)d_in[14];
  const float* bn1_g  = (const float*)d_in[16];
  const float* bn1_b  = (const float*)d_in[17];
  const float* c_w1   = (const float*)d_in[18];
  const float* c_b1   = (const float*)d_in[19];
  const float* cbn1_g = (const float*)d_in[20];
  const float* cbn1_b = (const float*)d_in[21];
  const float* c_w2   = (const float*)d_in[22];
  const float* c_b2   = (const float*)d_in[23];
  const float* cbn2_g = (const float*)d_in[24];
  const float* cbn2_b = (const float*)d_in[25];
  const float* c_w3   = (const float*)d_in[26];
  const float* c_b3   = (const float*)d_in[27];
  float* out = (float*)d_out;
  float* ws = (float*)d_ws;

  u16* xb   = (u16*)(ws + XB);
  u16* xl0b = (u16*)(ws + XL0B);
  u16* xr0b = (u16*)(ws + XR0B);
  u16* h0b  = (u16*)(ws + H0B);
  u16* wt0a = (u16*)(ws + WTS);
  u16* wt0b = wt0a + 131072;
  u16* wt1a = wt0a + 262144;
  u16* wt1b = wt0a + 393216;
  int* offs   = (int*)(ws + CSRI);
  int* cursor = offs + (Nn + 1);
  int* eidx   = cursor + Nn;

  hipMemsetAsync(cursor, 0, Nn * sizeof(int), stream);
  hipMemsetAsync(ws + SMALL, 0, ZCNT * sizeof(float), stream);

  // ---- conversions ----
  conv_bf<<<(Nn * 256 / 4 + 255) / 256, 256, 0, stream>>>(x, xb, Nn * 256 / 4);
  conv_wt<<<512, 256, 0, stream>>>(g0_wl, wt0a, 256, 512);
  conv_wt<<<512, 256, 0, stream>>>(g0_wr, wt0b, 256, 512);
  conv_wt<<<512, 256, 0, stream>>>(g1_wl, wt1a, 512, 256);
  conv_wt<<<512, 256, 0, stream>>>(g1_wr, wt1b, 512, 256);

  // ---- CSR by destination ----
  csr_hist<<<(Ee + 255) / 256, 256, 0, stream>>>(ei, cursor);
  csr_scan<<<1, 1024, 0, stream>>>(offs, cursor);
  csr_fill<<<(Ee + 255) / 256, 256, 0, stream>>>(ei, cursor, eidx);

  // ---- layer 0 ----
  gemm_mfma<<<dim3(4, 157, 2), 256, 0, stream>>>(xb, wt0a, wt0b, xl0b, xr0b,
                                                 Nn, 256, 512);
  score_l0<<<Ee / 4, 256, 0, stream>>>(xl0b, xr0b, ea, g0_we, g0_att, ei, ws + ESC);
  softmax_dst<<<(Nn * 4 + 255) / 256, 256, 0, stream>>>(ws + ESC, offs, eidx);
  aggregate_l0<<<Nn / 4, 256, 0, stream>>>(xl0b, ws + ESC, ei, offs, eidx, ws + OUT0);
  bn_reduce<<<200, 512, 0, stream>>>(ws + OUT0, ws + BN0S, Nn, 512, 100);
  bn_apply_bf<<<40000, 256, 0, stream>>>(ws + OUT0, ws + BN0S, bn0_g, bn0_b, h0b,
                                         Nn * 512, 512, 1.f / Nn);
  // ---- layer 1 (xl1/xr1 reuse xl0b/xr0b space) ----
  gemm_mfma<<<dim3(2, 157, 2), 256, 0, stream>>>(h0b, wt1a, wt1b, xl0b, xr0b,
                                                 Nn, 512, 256);
  score_l1<<<Ee / 4, 256, 0, stream>>>(xl0b, xr0b, ea, g1_we, g1_att, ei, ws + ESC);
  softmax_dst<<<(Nn * 4 + 255) / 256, 256, 0, stream>>>(ws + ESC, offs, eidx);
  aggregate_l1<<<Nn / 4, 256, 0, stream>>>(xl0b, ws + ESC, ei, offs, eidx, ws + OUT1);
  bn_reduce<<<50, 256, 0, stream>>>(ws + OUT1, ws + BN1S, Nn, 64, 400);
  bn_apply<<<5000, 256, 0, stream>>>(ws + OUT1, ws + BN1S, bn1_g, bn1_b,
                                     Nn * 64, 64, 1.f / Nn);
  // ---- pool + classifier ----
  pool_accum<<<Nn * 64 / 256, 256, 0, stream>>>(ws + OUT1, batch, ws + POOLS, ws + CNTS);
  mlp1<<<1, 256, 0, stream>>>(ws + POOLS, ws + CNTS, c_w1, c_b1, cbn1_g, cbn1_b,
                              ws + Z1, out + 128);
  mlp2<<<1, 128, 0, stream>>>(ws + Z1, c_w2, c_b2, cbn2_g, cbn2_b, ws + Z2);
  mlp3<<<1, 128, 0, stream>>>(ws + Z2, c_w3, c_b3, out);
}

// Round 4
// 885.018 us; speedup vs baseline: 6.2887x; 1.1337x over previous
//
#include <hip/hip_runtime.h>
#include <cmath>

#define Nn 20000
#define Ee 320000
#define Bb 64

typedef unsigned short u16;
typedef __bf16 bf16x8 __attribute__((ext_vector_type(8)));
typedef float f32x4 __attribute__((ext_vector_type(4)));

// ---------------- workspace layout (float units) ----------------
static const size_t OUT0 = 0;                    // N*512 fp32
static const size_t XL0B = 10240000;             // N*512 bf16 (layer1 reuses as N*256)
static const size_t XR0B = 15360000;             // N*512 bf16
static const size_t H0B  = 20480000;             // N*512 bf16 (post-BN h0)
static const size_t XB   = 25600000;             // N*256 bf16
static const size_t WTS  = 28160000;             // 4 x 131072 u16 (transposed bf16 weights)
static const size_t OUT1 = 28422144;             // N*64 fp32
static const size_t ESC  = 29702144;             // E*4 fp32
static const size_t CSRI = 30982144;             // ints: offs[N+1], cursor[N], eidx[E], goffs[B+1]
static const size_t SMALL= 31342272;
static const size_t BN0S = SMALL;                // 1024
static const size_t BN1S = BN0S + 1024;          // 128
static const size_t ZCNT = 1152;                 // floats to zero (BN stats only)
static const size_t EMB  = BN1S + 128;           // 64*64 emb
static const size_t Z1   = EMB + 4096;           // 64*256
static const size_t Z2   = Z1 + 16384;           // 64*128

__device__ __forceinline__ float lrelu(float x){ return x > 0.f ? x : 0.2f * x; }
__device__ __forceinline__ float elu(float x){ return x > 0.f ? x : expm1f(x); }
__device__ __forceinline__ u16 fbf(float f){           // fp32 -> bf16 RNE
  unsigned u = __float_as_uint(f);
  return (u16)((u + 0x7fffu + ((u >> 16) & 1u)) >> 16);
}
__device__ __forceinline__ float blo(unsigned u){ return __uint_as_float(u << 16); }
__device__ __forceinline__ float bhi(unsigned u){ return __uint_as_float(u & 0xffff0000u); }
__device__ __forceinline__ float b2f(u16 v){ return __uint_as_float(((unsigned)v) << 16); }

// ---------------- fp32 -> bf16 (n multiple of 4) ----------------
__global__ __launch_bounds__(256) void conv_bf(const float* __restrict__ src,
                                               u16* __restrict__ dst, int n4){
  int i = blockIdx.x * 256 + threadIdx.x;
  if (i < n4){
    float4 v = ((const float4*)src)[i];
    ushort4 o; o.x = fbf(v.x); o.y = fbf(v.y); o.z = fbf(v.z); o.w = fbf(v.w);
    ((ushort4*)dst)[i] = o;
  }
}

// ---------------- W[K][N] fp32 -> WT[N][K] bf16 ----------------
__global__ __launch_bounds__(256) void conv_wt(const float* __restrict__ W,
                                               u16* __restrict__ WT, int K, int N){
  int i = blockIdx.x * 256 + threadIdx.x;
  if (i < K * N){
    int n = i / K, k = i - n * K;
    WT[i] = fbf(W[k * N + n]);
  }
}

// ---------------- MFMA GEMM: O[M][Nc] = A[M][K] @ WT[Nc][K]^T, all bf16, fp32 acc
__global__ __launch_bounds__(256) void gemm_mfma(const u16* __restrict__ A,
    const u16* __restrict__ WTa, const u16* __restrict__ WTb,
    u16* __restrict__ Oa, u16* __restrict__ Ob, int M, int K, int Nc){
  const u16* WT = blockIdx.z ? WTb : WTa;
  u16* O = blockIdx.z ? Ob : Oa;
  __shared__ u16 As[128 * 40];   // row stride 40 u16 = 80B -> 2-way bank alias (free)
  __shared__ u16 Bs[128 * 40];
  int tid = threadIdx.x;
  int m0 = blockIdx.y * 128, n0 = blockIdx.x * 128;
  int lane = tid & 63, w = tid >> 6;
  int wr = (w >> 1) * 64, wc = (w & 1) * 64;
  int l16 = lane & 15, kq = lane >> 4;
  f32x4 acc[4][4] = {};
  int srow = tid >> 2, scol = (tid & 3) * 8;
  for (int kt = 0; kt < K; kt += 32){
    #pragma unroll
    for (int r = 0; r < 2; r++){
      int row = r * 64 + srow;
      uint4 av = make_uint4(0u, 0u, 0u, 0u);
      int gr = m0 + row;
      if (gr < M) av = *(const uint4*)&A[(size_t)gr * K + kt + scol];
      *(uint4*)&As[row * 40 + scol] = av;
      uint4 bv = *(const uint4*)&WT[(size_t)(n0 + row) * K + kt + scol];
      *(uint4*)&Bs[row * 40 + scol] = bv;
    }
    __syncthreads();
    bf16x8 af[4], bfr[4];
    #pragma unroll
    for (int i = 0; i < 4; i++){
      af[i]  = *(bf16x8*)&As[(wr + i * 16 + l16) * 40 + kq * 8];
      bfr[i] = *(bf16x8*)&Bs[(wc + i * 16 + l16) * 40 + kq * 8];
    }
    #pragma unroll
    for (int i = 0; i < 4; i++)
      #pragma unroll
      for (int j = 0; j < 4; j++)
        acc[i][j] = __builtin_amdgcn_mfma_f32_16x16x32_bf16(af[i], bfr[j], acc[i][j], 0, 0, 0);
    __syncthreads();
  }
  #pragma unroll
  for (int i = 0; i < 4; i++){
    #pragma unroll
    for (int rg = 0; rg < 4; rg++){
      int row = m0 + wr + i * 16 + kq * 4 + rg;
      if (row < M){
        #pragma unroll
        for (int j = 0; j < 4; j++){
          int col = n0 + wc + j * 16 + l16;
          O[(size_t)row * Nc + col] = fbf(acc[i][j][rg]);
        }
      }
    }
  }
}

// ---------------- CSR build ----------------
__global__ __launch_bounds__(256) void csr_hist(const int* __restrict__ ei,
                                                int* __restrict__ cursor){
  int e = blockIdx.x * 256 + threadIdx.x;
  if (e < Ee) atomicAdd(&cursor[ei[Ee + e]], 1);
}

__global__ __launch_bounds__(1024) void csr_scan(int* __restrict__ offs,
                                                 int* __restrict__ cursor){
  __shared__ int part[1024];
  int t = threadIdx.x;
  int base = t * 20;
  int loc[20];
  int s = 0;
  #pragma unroll
  for (int i = 0; i < 20; i++){
    int idx = base + i;
    int v = (idx < Nn) ? cursor[idx] : 0;
    loc[i] = s; s += v;
  }
  part[t] = s;
  __syncthreads();
  for (int off = 1; off < 1024; off <<= 1){
    int v = 0;
    if (t >= off) v = part[t - off];
    __syncthreads();
    if (t >= off) part[t] += v;
    __syncthreads();
  }
  int pre = (t == 0) ? 0 : part[t - 1];
  #pragma unroll
  for (int i = 0; i < 20; i++){
    int idx = base + i;
    if (idx < Nn){ offs[idx] = pre + loc[i]; cursor[idx] = pre + loc[i]; }
  }
  if (t == 1023) offs[Nn] = part[1023];
}

__global__ __launch_bounds__(256) void csr_fill(const int* __restrict__ ei,
    int* __restrict__ cursor, int* __restrict__ eidx){
  int e = blockIdx.x * 256 + threadIdx.x;
  if (e < Ee){
    int d = ei[Ee + e];
    int p = atomicAdd(&cursor[d], 1);
    eidx[p] = e;
  }
}

// ---------------- graph boundaries from sorted batch: goffs[b] = first row with batch>=b
__global__ __launch_bounds__(256) void graph_bounds(const int* __restrict__ batch,
                                                    int* __restrict__ goffs){
  int i = blockIdx.x * 256 + threadIdx.x;
  if (i >= Nn) return;
  int b1 = batch[i];
  int b0 = (i == 0) ? -1 : batch[i - 1];
  for (int b = b0 + 1; b <= b1; b++) goffs[b] = i;
  if (i == Nn - 1)
    for (int b = b1 + 1; b <= Bb; b++) goffs[b] = Nn;
}

// ---------------- layer-0 edge scores (bf16 xl/xr, 512 ch), wave/edge
__global__ __launch_bounds__(256) void score_l0(const u16* __restrict__ xl,
    const u16* __restrict__ xr, const float* __restrict__ ea,
    const float* __restrict__ we, const float* __restrict__ att,
    const int* __restrict__ ei, float* __restrict__ esc){
  int eid = blockIdx.x * 4 + (threadIdx.x >> 6);
  int lane = threadIdx.x & 63;
  int src = ei[eid], dst = ei[Ee + eid];
  float a = ea[eid];
  int c = lane << 3;
  uint4 lu = *(const uint4*)&xl[(size_t)src * 512 + c];
  uint4 ru = *(const uint4*)&xr[(size_t)dst * 512 + c];
  float4 w0 = *(const float4*)&we[c],  w1 = *(const float4*)&we[c + 4];
  float4 t0 = *(const float4*)&att[c], t1 = *(const float4*)&att[c + 4];
  float p = 0.f;
  p += lrelu(blo(lu.x) + blo(ru.x) + a * w0.x) * t0.x;
  p += lrelu(bhi(lu.x) + bhi(ru.x) + a * w0.y) * t0.y;
  p += lrelu(blo(lu.y) + blo(ru.y) + a * w0.z) * t0.z;
  p += lrelu(bhi(lu.y) + bhi(ru.y) + a * w0.w) * t0.w;
  p += lrelu(blo(lu.z) + blo(ru.z) + a * w1.x) * t1.x;
  p += lrelu(bhi(lu.z) + bhi(ru.z) + a * w1.y) * t1.y;
  p += lrelu(blo(lu.w) + blo(ru.w) + a * w1.z) * t1.z;
  p += lrelu(bhi(lu.w) + bhi(ru.w) + a * w1.w) * t1.w;
  p += __shfl_xor(p, 8); p += __shfl_xor(p, 4);
  p += __shfl_xor(p, 2); p += __shfl_xor(p, 1);
  if ((lane & 15) == 0) esc[eid * 4 + (lane >> 4)] = p;
}

// ---------------- layer-1 edge scores (bf16, 256 ch)
__global__ __launch_bounds__(256) void score_l1(const u16* __restrict__ xl,
    const u16* __restrict__ xr, const float* __restrict__ ea,
    const float* __restrict__ we, const float* __restrict__ att,
    const int* __restrict__ ei, float* __restrict__ esc){
  int eid = blockIdx.x * 4 + (threadIdx.x >> 6);
  int lane = threadIdx.x & 63;
  int src = ei[eid], dst = ei[Ee + eid];
  float a = ea[eid];
  int c = lane << 2;
  uint2 lu = *(const uint2*)&xl[(size_t)src * 256 + c];
  uint2 ru = *(const uint2*)&xr[(size_t)dst * 256 + c];
  float4 w = *(const float4*)&we[c];
  float4 t = *(const float4*)&att[c];
  float p = 0.f;
  p += lrelu(blo(lu.x) + blo(ru.x) + a * w.x) * t.x;
  p += lrelu(bhi(lu.x) + bhi(ru.x) + a * w.y) * t.y;
  p += lrelu(blo(lu.y) + blo(ru.y) + a * w.z) * t.z;
  p += lrelu(bhi(lu.y) + bhi(ru.y) + a * w.w) * t.w;
  p += __shfl_xor(p, 8); p += __shfl_xor(p, 4);
  p += __shfl_xor(p, 2); p += __shfl_xor(p, 1);
  if ((lane & 15) == 0) esc[eid * 4 + (lane >> 4)] = p;
}

// ---------------- per-dst softmax over incoming edges
__global__ __launch_bounds__(256) void softmax_dst(float* __restrict__ esc,
    const int* __restrict__ offs, const int* __restrict__ eidx){
  int idx = blockIdx.x * 256 + threadIdx.x;
  if (idx >= Nn * 4) return;
  int n = idx >> 2, h = idx & 3;
  int s = offs[n], e = offs[n + 1];
  if (s == e) return;
  float m = -INFINITY;
  for (int i = s; i < e; i++) m = fmaxf(m, esc[eidx[i] * 4 + h]);
  float den = 0.f;
  for (int i = s; i < e; i++){
    int id = eidx[i] * 4 + h;
    float v = expf(esc[id] - m);
    esc[id] = v; den += v;
  }
  float inv = 1.f / (den + 1e-16f);
  for (int i = s; i < e; i++) esc[eidx[i] * 4 + h] *= inv;
}

// ---------------- layer-0 aggregation (bf16 gather, fp32 out), wave/dst
__global__ __launch_bounds__(256) void aggregate_l0(const u16* __restrict__ xl,
    const float* __restrict__ esc, const int* __restrict__ ei,
    const int* __restrict__ offs, const int* __restrict__ eidx,
    float* __restrict__ out){
  int n = blockIdx.x * 4 + (threadIdx.x >> 6);
  int lane = threadIdx.x & 63;
  int s = offs[n], e = offs[n + 1];
  int c = lane << 3, h = lane >> 4;
  float a0=0.f,a1=0.f,a2=0.f,a3=0.f,a4=0.f,a5=0.f,a6=0.f,a7=0.f;
  for (int i = s; i < e; i++){
    int eid = eidx[i];
    float alpha = esc[eid * 4 + h];
    int src = ei[eid];
    uint4 v = *(const uint4*)&xl[(size_t)src * 512 + c];
    a0 += alpha * blo(v.x); a1 += alpha * bhi(v.x);
    a2 += alpha * blo(v.y); a3 += alpha * bhi(v.y);
    a4 += alpha * blo(v.z); a5 += alpha * bhi(v.z);
    a6 += alpha * blo(v.w); a7 += alpha * bhi(v.w);
  }
  float4* op = (float4*)&out[(size_t)n * 512 + c];
  op[0] = make_float4(a0, a1, a2, a3);
  op[1] = make_float4(a4, a5, a6, a7);
}

// ---------------- layer-1 aggregation, head-mean folded, wave/dst
__global__ __launch_bounds__(256) void aggregate_l1(const u16* __restrict__ xl,
    const float* __restrict__ esc, const int* __restrict__ ei,
    const int* __restrict__ offs, const int* __restrict__ eidx,
    float* __restrict__ out){
  int n = blockIdx.x * 4 + (threadIdx.x >> 6);
  int lane = threadIdx.x & 63;   // output channel
  int s = offs[n], e = offs[n + 1];
  float acc = 0.f;
  for (int i = s; i < e; i++){
    int eid = eidx[i];
    int src = ei[eid];
    float4 al = *(const float4*)&esc[eid * 4];
    const u16* xp = &xl[(size_t)src * 256 + lane];
    acc += al.x * 0.25f * b2f(xp[0]);
    acc += al.y * 0.25f * b2f(xp[64]);
    acc += al.z * 0.25f * b2f(xp[128]);
    acc += al.w * 0.25f * b2f(xp[192]);
  }
  out[(size_t)n * 64 + lane] = acc;
}

// ---------------- batchnorm reduce
__global__ void bn_reduce(const float* __restrict__ X, float* __restrict__ stats,
                          int Nr, int C, int rpb){
  int tid = threadIdx.x;
  int c = tid % C, sub = tid / C, step = blockDim.x / C;
  float s = 0.f, s2 = 0.f;
  int rend = min((int)((blockIdx.x + 1) * rpb), Nr);
  for (int r = blockIdx.x * rpb + sub; r < rend; r += step){
    float v = X[(size_t)r * C + c];
    s += v; s2 += v * v;
  }
  atomicAdd(&stats[c], s);
  atomicAdd(&stats[C + c], s2);
}

// ---------------- BN+ELU -> bf16 out (layer 0 path feeds MFMA GEMM)
__global__ __launch_bounds__(256) void bn_apply_bf(const float* __restrict__ X,
    const float* __restrict__ stats, const float* __restrict__ g,
    const float* __restrict__ b, u16* __restrict__ Xb, int total, int C, float invN){
  int idx = blockIdx.x * 256 + threadIdx.x;
  if (idx >= total) return;
  int c = idx % C;
  float mean = stats[c] * invN;
  float var = stats[C + c] * invN - mean * mean;
  float inv = rsqrtf(var + 1e-5f);
  float v = (X[idx] - mean) * inv * g[c] + b[c];
  Xb[idx] = fbf(elu(v));
}

// ---------------- BN+ELU fp32 in place (layer 1 path)
__global__ __launch_bounds__(256) void bn_apply(float* __restrict__ X,
    const float* __restrict__ stats, const float* __restrict__ g,
    const float* __restrict__ b, int total, int C, float invN){
  int idx = blockIdx.x * 256 + threadIdx.x;
  if (idx >= total) return;
  int c = idx % C;
  float mean = stats[c] * invN;
  float var = stats[C + c] * invN - mean * mean;
  float inv = rsqrtf(var + 1e-5f);
  float v = (X[idx] - mean) * inv * g[c] + b[c];
  X[idx] = elu(v);
}

// ---------------- per-graph mean pool (block per graph, no atomics)
__global__ __launch_bounds__(256) void pool_graph(const float* __restrict__ h1,
    const int* __restrict__ goffs, float* __restrict__ emb, float* __restrict__ out_emb){
  int b = blockIdx.x;
  int s = goffs[b], e = goffs[b + 1];
  int c = threadIdx.x & 63, sub = threadIdx.x >> 6;
  float acc = 0.f;
  for (int n = s + sub; n < e; n += 4) acc += h1[(size_t)n * 64 + c];
  __shared__ float red[4][64];
  red[sub][c] = acc;
  __syncthreads();
  if (sub == 0){
    float v = red[0][c] + red[1][c] + red[2][c] + red[3][c];
    v /= fmaxf((float)(e - s), 1.0f);
    emb[b * 64 + c] = v;
    out_emb[b * 64 + c] = v;
  }
}

// ---------------- classifier ----------------
__global__ __launch_bounds__(256) void mlp1(const float* __restrict__ embg,
    const float* __restrict__ W1, const float* __restrict__ b1,
    const float* __restrict__ g, const float* __restrict__ bb,
    float* __restrict__ z1){
  __shared__ float emb[64][64];
  int tid = threadIdx.x;
  for (int i = tid; i < 4096; i += 256) emb[i >> 6][i & 63] = embg[i];
  __syncthreads();
  int j = tid;
  float z[64];
  #pragma unroll
  for (int b = 0; b < 64; b++) z[b] = b1[j];
  for (int k = 0; k < 64; k++){
    float w = W1[k * 256 + j];
    #pragma unroll
    for (int b = 0; b < 64; b++) z[b] += emb[b][k] * w;
  }
  float s = 0.f, s2 = 0.f;
  #pragma unroll
  for (int b = 0; b < 64; b++){ s += z[b]; s2 += z[b] * z[b]; }
  float mean = s * (1.f/64.f);
  float var = s2 * (1.f/64.f) - mean * mean;
  float inv = rsqrtf(var + 1e-5f);
  float sc = g[j] * inv, sh = bb[j] - mean * sc;
  #pragma unroll
  for (int b = 0; b < 64; b++) z1[b * 256 + j] = elu(z[b] * sc + sh);
}

__global__ __launch_bounds__(128) void mlp2(const float* __restrict__ z1,
    const float* __restrict__ W2, const float* __restrict__ b2,
    const float* __restrict__ g, const float* __restrict__ bb, float* __restrict__ z2){
  int j = threadIdx.x;
  float acc[64];
  #pragma unroll
  for (int b = 0; b < 64; b++) acc[b] = b2[j];
  for (int k = 0; k < 256; k++){
    float w = W2[k * 128 + j];
    #pragma unroll
    for (int b = 0; b < 64; b++) acc[b] += z1[b * 256 + k] * w;
  }
  float s = 0.f, s2 = 0.f;
  #pragma unroll
  for (int b = 0; b < 64; b++){ s += acc[b]; s2 += acc[b] * acc[b]; }
  float mean = s * (1.f/64.f);
  float var = s2 * (1.f/64.f) - mean * mean;
  float inv = rsqrtf(var + 1e-5f);
  float sc = g[j] * inv, sh = bb[j] - mean * sc;
  #pragma unroll
  for (int b = 0; b < 64; b++) z2[b * 128 + j] = elu(acc[b] * sc + sh);
}

__global__ __launch_bounds__(128) void mlp3(const float* __restrict__ z2,
    const float* __restrict__ W3, const float* __restrict__ b3, float* __restrict__ out){
  int tid = threadIdx.x;
  int b = tid >> 1, o = tid & 1;
  float acc = b3[o];
  for (int k = 0; k < 128; k++) acc += z2[b * 128 + k] * W3[k * 2 + o];
  out[b * 2 + o] = acc;
}

extern "C" void kernel_launch(void* const* d_in, const int* in_sizes, int n_in,
                              void* d_out, int out_size, void* d_ws, size_t ws_size,
                              hipStream_t stream){
  const float* x      = (const float*)d_in[0];
  const int*   ei     = (const int*)d_in[1];
  const float* ea     = (const float*)d_in[2];
  const int*   batch  = (const int*)d_in[3];
  const float* g0_wl  = (const float*)d_in[4];
  const float* g0_wr  = (const float*)d_in[5];
  const float* g0_we  = (const float*)d_in[6];
  const float* g0_att = (const float*)d_in[7];
  const float* bn0_g  = (const float*)d_in[9];
  const float* bn0_b  = (const float*)d_in[10];
  const float* g1_wl  = (const float*)d_in[11];
  const float* g1_wr  = (const float*)d_in[12];
  const float* g1_we  = (const float*)d_in[13];
  const float* g1_att = (const float*)d_in[14];
  const float* bn1_g  = (const float*)d_in[16];
  const float* bn1_b  = (const float*)d_in[17];
  const float* c_w1   = (const float*)d_in[18];
  const float* c_b1   = (const float*)d_in[19];
  const float* cbn1_g = (const float*)d_in[20];
  const float* cbn1_b = (const float*)d_in[21];
  const float* c_w2   = (const float*)d_in[22];
  const float* c_b2   = (const float*)d_in[23];
  const float* cbn2_g = (const float*)d_in[24];
  const float* cbn2_b = (const float*)d_in[25];
  const float* c_w3   = (const float*)d_in[26];
  const float* c_b3   = (const float*)d_in[27];
  float* out = (float*)d_out;
  float* ws = (float*)d_ws;

  u16* xb   = (u16*)(ws + XB);
  u16* xl0b = (u16*)(ws + XL0B);
  u16* xr0b = (u16*)(ws + XR0B);
  u16* h0b  = (u16*)(ws + H0B);
  u16* wt0a = (u16*)(ws + WTS);
  u16* wt0b = wt0a + 131072;
  u16* wt1a = wt0a + 262144;
  u16* wt1b = wt0a + 393216;
  int* offs   = (int*)(ws + CSRI);
  int* cursor = offs + (Nn + 1);
  int* eidx   = cursor + Nn;
  int* goffs  = eidx + Ee;          // B+1

  hipMemsetAsync(cursor, 0, Nn * sizeof(int), stream);
  hipMemsetAsync(ws + SMALL, 0, ZCNT * sizeof(float), stream);

  // ---- conversions ----
  conv_bf<<<(Nn * 256 / 4 + 255) / 256, 256, 0, stream>>>(x, xb, Nn * 256 / 4);
  conv_wt<<<512, 256, 0, stream>>>(g0_wl, wt0a, 256, 512);
  conv_wt<<<512, 256, 0, stream>>>(g0_wr, wt0b, 256, 512);
  conv_wt<<<512, 256, 0, stream>>>(g1_wl, wt1a, 512, 256);
  conv_wt<<<512, 256, 0, stream>>>(g1_wr, wt1b, 512, 256);

  // ---- CSR by destination + graph bounds ----
  csr_hist<<<(Ee + 255) / 256, 256, 0, stream>>>(ei, cursor);
  csr_scan<<<1, 1024, 0, stream>>>(offs, cursor);
  csr_fill<<<(Ee + 255) / 256, 256, 0, stream>>>(ei, cursor, eidx);
  graph_bounds<<<(Nn + 255) / 256, 256, 0, stream>>>(batch, goffs);

  // ---- layer 0 ----
  gemm_mfma<<<dim3(4, 157, 2), 256, 0, stream>>>(xb, wt0a, wt0b, xl0b, xr0b,
                                                 Nn, 256, 512);
  score_l0<<<Ee / 4, 256, 0, stream>>>(xl0b, xr0b, ea, g0_we, g0_att, ei, ws + ESC);
  softmax_dst<<<(Nn * 4 + 255) / 256, 256, 0, stream>>>(ws + ESC, offs, eidx);
  aggregate_l0<<<Nn / 4, 256, 0, stream>>>(xl0b, ws + ESC, ei, offs, eidx, ws + OUT0);
  bn_reduce<<<200, 512, 0, stream>>>(ws + OUT0, ws + BN0S, Nn, 512, 100);
  bn_apply_bf<<<40000, 256, 0, stream>>>(ws + OUT0, ws + BN0S, bn0_g, bn0_b, h0b,
                                         Nn * 512, 512, 1.f / Nn);
  // ---- layer 1 ----
  gemm_mfma<<<dim3(2, 157, 2), 256, 0, stream>>>(h0b, wt1a, wt1b, xl0b, xr0b,
                                                 Nn, 512, 256);
  score_l1<<<Ee / 4, 256, 0, stream>>>(xl0b, xr0b, ea, g1_we, g1_att, ei, ws + ESC);
  softmax_dst<<<(Nn * 4 + 255) / 256, 256, 0, stream>>>(ws + ESC, offs, eidx);
  aggregate_l1<<<Nn / 4, 256, 0, stream>>>(xl0b, ws + ESC, ei, offs, eidx, ws + OUT1);
  bn_reduce<<<50, 256, 0, stream>>>(ws + OUT1, ws + BN1S, Nn, 64, 400);
  bn_apply<<<5000, 256, 0, stream>>>(ws + OUT1, ws + BN1S, bn1_g, bn1_b,
                                     Nn * 64, 64, 1.f / Nn);
  // ---- pool + classifier ----
  pool_graph<<<Bb, 256, 0, stream>>>(ws + OUT1, goffs, ws + EMB, out + 128);
  mlp1<<<1, 256, 0, stream>>>(ws + EMB, c_w1, c_b1, cbn1_g, cbn1_b, ws + Z1);
  mlp2<<<1, 128, 0, stream>>>(ws + Z1, c_w2, c_b2, cbn2_g, cbn2_b, ws + Z2);
  mlp3<<<1, 128, 0, stream>>>(ws + Z2, c_w3, c_b3, out);
}

// Round 5
// 819.621 us; speedup vs baseline: 6.7904x; 1.0798x over previous
//
#include <hip/hip_runtime.h>
#include <cmath>

#define Nn 20000
#define Ee 320000
#define Bb 64

typedef unsigned short u16;
typedef __bf16 bf16x8 __attribute__((ext_vector_type(8)));
typedef float f32x4 __attribute__((ext_vector_type(4)));

// ---------------- workspace layout (float units) ----------------
static const size_t OUT0 = 0;                    // N*512 fp32
static const size_t XL0B = 10240000;             // N*512 bf16 (layer1 reuses as N*256)
static const size_t XR0B = 15360000;             // N*512 bf16
static const size_t H0B  = 20480000;             // N*512 bf16 (post-BN h0)
static const size_t XB   = 25600000;             // N*256 bf16
static const size_t WTS  = 28160000;             // 4 x 131072 u16 (transposed bf16 weights)
static const size_t OUT1 = 28422144;             // N*64 fp32
static const size_t ESC  = 29702144;             // E*4 fp32
static const size_t CSRI = 30982144;             // ints: offs[N+1], cursor[N], eidx[E], goffs[B+1]
static const size_t SMALL= 31342272;
static const size_t BN0S = SMALL;                // 1024
static const size_t BN1S = BN0S + 1024;          // 128
static const size_t ZCNT = 1152;                 // floats to zero (BN stats only)
static const size_t EMB  = BN1S + 128;           // 64*64 emb

__device__ __forceinline__ float lrelu(float x){ return x > 0.f ? x : 0.2f * x; }
__device__ __forceinline__ float elu(float x){ return x > 0.f ? x : expm1f(x); }
__device__ __forceinline__ u16 fbf(float f){           // fp32 -> bf16 RNE
  unsigned u = __float_as_uint(f);
  return (u16)((u + 0x7fffu + ((u >> 16) & 1u)) >> 16);
}
__device__ __forceinline__ float blo(unsigned u){ return __uint_as_float(u << 16); }
__device__ __forceinline__ float bhi(unsigned u){ return __uint_as_float(u & 0xffff0000u); }
__device__ __forceinline__ float b2f(u16 v){ return __uint_as_float(((unsigned)v) << 16); }

// ---------------- fp32 -> bf16 (n multiple of 4) ----------------
__global__ __launch_bounds__(256) void conv_bf(const float* __restrict__ src,
                                               u16* __restrict__ dst, int n4){
  int i = blockIdx.x * 256 + threadIdx.x;
  if (i < n4){
    float4 v = ((const float4*)src)[i];
    ushort4 o; o.x = fbf(v.x); o.y = fbf(v.y); o.z = fbf(v.z); o.w = fbf(v.w);
    ((ushort4*)dst)[i] = o;
  }
}

// ---------------- W[K][N] fp32 -> WT[N][K] bf16 ----------------
__global__ __launch_bounds__(256) void conv_wt(const float* __restrict__ W,
                                               u16* __restrict__ WT, int K, int N){
  int i = blockIdx.x * 256 + threadIdx.x;
  if (i < K * N){
    int n = i / K, k = i - n * K;
    WT[i] = fbf(W[k * N + n]);
  }
}

// ---------------- MFMA GEMM: O[M][Nc] = A[M][K] @ WT[Nc][K]^T, all bf16, fp32 acc
__global__ __launch_bounds__(256) void gemm_mfma(const u16* __restrict__ A,
    const u16* __restrict__ WTa, const u16* __restrict__ WTb,
    u16* __restrict__ Oa, u16* __restrict__ Ob, int M, int K, int Nc){
  const u16* WT = blockIdx.z ? WTb : WTa;
  u16* O = blockIdx.z ? Ob : Oa;
  __shared__ u16 As[128 * 40];   // row stride 40 u16 = 80B -> 2-way bank alias (free)
  __shared__ u16 Bs[128 * 40];
  int tid = threadIdx.x;
  int m0 = blockIdx.y * 128, n0 = blockIdx.x * 128;
  int lane = tid & 63, w = tid >> 6;
  int wr = (w >> 1) * 64, wc = (w & 1) * 64;
  int l16 = lane & 15, kq = lane >> 4;
  f32x4 acc[4][4] = {};
  int srow = tid >> 2, scol = (tid & 3) * 8;
  for (int kt = 0; kt < K; kt += 32){
    #pragma unroll
    for (int r = 0; r < 2; r++){
      int row = r * 64 + srow;
      uint4 av = make_uint4(0u, 0u, 0u, 0u);
      int gr = m0 + row;
      if (gr < M) av = *(const uint4*)&A[(size_t)gr * K + kt + scol];
      *(uint4*)&As[row * 40 + scol] = av;
      uint4 bv = *(const uint4*)&WT[(size_t)(n0 + row) * K + kt + scol];
      *(uint4*)&Bs[row * 40 + scol] = bv;
    }
    __syncthreads();
    bf16x8 af[4], bfr[4];
    #pragma unroll
    for (int i = 0; i < 4; i++){
      af[i]  = *(bf16x8*)&As[(wr + i * 16 + l16) * 40 + kq * 8];
      bfr[i] = *(bf16x8*)&Bs[(wc + i * 16 + l16) * 40 + kq * 8];
    }
    #pragma unroll
    for (int i = 0; i < 4; i++)
      #pragma unroll
      for (int j = 0; j < 4; j++)
        acc[i][j] = __builtin_amdgcn_mfma_f32_16x16x32_bf16(af[i], bfr[j], acc[i][j], 0, 0, 0);
    __syncthreads();
  }
  #pragma unroll
  for (int i = 0; i < 4; i++){
    #pragma unroll
    for (int rg = 0; rg < 4; rg++){
      int row = m0 + wr + i * 16 + kq * 4 + rg;
      if (row < M){
        #pragma unroll
        for (int j = 0; j < 4; j++){
          int col = n0 + wc + j * 16 + l16;
          O[(size_t)row * Nc + col] = fbf(acc[i][j][rg]);
        }
      }
    }
  }
}

// ---------------- CSR build ----------------
__global__ __launch_bounds__(256) void csr_hist(const int* __restrict__ ei,
                                                int* __restrict__ cursor){
  int e = blockIdx.x * 256 + threadIdx.x;
  if (e < Ee) atomicAdd(&cursor[ei[Ee + e]], 1);
}

__global__ __launch_bounds__(1024) void csr_scan(int* __restrict__ offs,
                                                 int* __restrict__ cursor){
  __shared__ int part[1024];
  int t = threadIdx.x;
  int base = t * 20;
  int loc[20];
  int s = 0;
  #pragma unroll
  for (int i = 0; i < 20; i++){
    int idx = base + i;
    int v = (idx < Nn) ? cursor[idx] : 0;
    loc[i] = s; s += v;
  }
  part[t] = s;
  __syncthreads();
  for (int off = 1; off < 1024; off <<= 1){
    int v = 0;
    if (t >= off) v = part[t - off];
    __syncthreads();
    if (t >= off) part[t] += v;
    __syncthreads();
  }
  int pre = (t == 0) ? 0 : part[t - 1];
  #pragma unroll
  for (int i = 0; i < 20; i++){
    int idx = base + i;
    if (idx < Nn){ offs[idx] = pre + loc[i]; cursor[idx] = pre + loc[i]; }
  }
  if (t == 1023) offs[Nn] = part[1023];
}

__global__ __launch_bounds__(256) void csr_fill(const int* __restrict__ ei,
    int* __restrict__ cursor, int* __restrict__ eidx){
  int e = blockIdx.x * 256 + threadIdx.x;
  if (e < Ee){
    int d = ei[Ee + e];
    int p = atomicAdd(&cursor[d], 1);
    eidx[p] = e;
  }
}

// ---------------- graph boundaries from sorted batch
__global__ __launch_bounds__(256) void graph_bounds(const int* __restrict__ batch,
                                                    int* __restrict__ goffs){
  int i = blockIdx.x * 256 + threadIdx.x;
  if (i >= Nn) return;
  int b1 = batch[i];
  int b0 = (i == 0) ? -1 : batch[i - 1];
  for (int b = b0 + 1; b <= b1; b++) goffs[b] = i;
  if (i == Nn - 1)
    for (int b = b1 + 1; b <= Bb; b++) goffs[b] = Nn;
}

// ---------------- layer-0 edge scores (bf16 xl/xr, 512 ch), wave/edge
__global__ __launch_bounds__(256) void score_l0(const u16* __restrict__ xl,
    const u16* __restrict__ xr, const float* __restrict__ ea,
    const float* __restrict__ we, const float* __restrict__ att,
    const int* __restrict__ ei, float* __restrict__ esc){
  int eid = blockIdx.x * 4 + (threadIdx.x >> 6);
  int lane = threadIdx.x & 63;
  int src = ei[eid], dst = ei[Ee + eid];
  float a = ea[eid];
  int c = lane << 3;
  uint4 lu = *(const uint4*)&xl[(size_t)src * 512 + c];
  uint4 ru = *(const uint4*)&xr[(size_t)dst * 512 + c];
  float4 w0 = *(const float4*)&we[c],  w1 = *(const float4*)&we[c + 4];
  float4 t0 = *(const float4*)&att[c], t1 = *(const float4*)&att[c + 4];
  float p = 0.f;
  p += lrelu(blo(lu.x) + blo(ru.x) + a * w0.x) * t0.x;
  p += lrelu(bhi(lu.x) + bhi(ru.x) + a * w0.y) * t0.y;
  p += lrelu(blo(lu.y) + blo(ru.y) + a * w0.z) * t0.z;
  p += lrelu(bhi(lu.y) + bhi(ru.y) + a * w0.w) * t0.w;
  p += lrelu(blo(lu.z) + blo(ru.z) + a * w1.x) * t1.x;
  p += lrelu(bhi(lu.z) + bhi(ru.z) + a * w1.y) * t1.y;
  p += lrelu(blo(lu.w) + blo(ru.w) + a * w1.z) * t1.z;
  p += lrelu(bhi(lu.w) + bhi(ru.w) + a * w1.w) * t1.w;
  p += __shfl_xor(p, 8); p += __shfl_xor(p, 4);
  p += __shfl_xor(p, 2); p += __shfl_xor(p, 1);
  if ((lane & 15) == 0) esc[eid * 4 + (lane >> 4)] = p;
}

// ---------------- layer-1 edge scores (bf16, 256 ch)
__global__ __launch_bounds__(256) void score_l1(const u16* __restrict__ xl,
    const u16* __restrict__ xr, const float* __restrict__ ea,
    const float* __restrict__ we, const float* __restrict__ att,
    const int* __restrict__ ei, float* __restrict__ esc){
  int eid = blockIdx.x * 4 + (threadIdx.x >> 6);
  int lane = threadIdx.x & 63;
  int src = ei[eid], dst = ei[Ee + eid];
  float a = ea[eid];
  int c = lane << 2;
  uint2 lu = *(const uint2*)&xl[(size_t)src * 256 + c];
  uint2 ru = *(const uint2*)&xr[(size_t)dst * 256 + c];
  float4 w = *(const float4*)&we[c];
  float4 t = *(const float4*)&att[c];
  float p = 0.f;
  p += lrelu(blo(lu.x) + blo(ru.x) + a * w.x) * t.x;
  p += lrelu(bhi(lu.x) + bhi(ru.x) + a * w.y) * t.y;
  p += lrelu(blo(lu.y) + blo(ru.y) + a * w.z) * t.z;
  p += lrelu(bhi(lu.y) + bhi(ru.y) + a * w.w) * t.w;
  p += __shfl_xor(p, 8); p += __shfl_xor(p, 4);
  p += __shfl_xor(p, 2); p += __shfl_xor(p, 1);
  if ((lane & 15) == 0) esc[eid * 4 + (lane >> 4)] = p;
}

// ---------------- per-dst softmax over incoming edges
__global__ __launch_bounds__(256) void softmax_dst(float* __restrict__ esc,
    const int* __restrict__ offs, const int* __restrict__ eidx){
  int idx = blockIdx.x * 256 + threadIdx.x;
  if (idx >= Nn * 4) return;
  int n = idx >> 2, h = idx & 3;
  int s = offs[n], e = offs[n + 1];
  if (s == e) return;
  float m = -INFINITY;
  for (int i = s; i < e; i++) m = fmaxf(m, esc[eidx[i] * 4 + h]);
  float den = 0.f;
  for (int i = s; i < e; i++){
    int id = eidx[i] * 4 + h;
    float v = expf(esc[id] - m);
    esc[id] = v; den += v;
  }
  float inv = 1.f / (den + 1e-16f);
  for (int i = s; i < e; i++) esc[eidx[i] * 4 + h] *= inv;
}

// ---------------- layer-0 aggregation (bf16 gather, fp32 out), wave/dst
__global__ __launch_bounds__(256) void aggregate_l0(const u16* __restrict__ xl,
    const float* __restrict__ esc, const int* __restrict__ ei,
    const int* __restrict__ offs, const int* __restrict__ eidx,
    float* __restrict__ out){
  int n = blockIdx.x * 4 + (threadIdx.x >> 6);
  int lane = threadIdx.x & 63;
  int s = offs[n], e = offs[n + 1];
  int c = lane << 3, h = lane >> 4;
  float a0=0.f,a1=0.f,a2=0.f,a3=0.f,a4=0.f,a5=0.f,a6=0.f,a7=0.f;
  for (int i = s; i < e; i++){
    int eid = eidx[i];
    float alpha = esc[eid * 4 + h];
    int src = ei[eid];
    uint4 v = *(const uint4*)&xl[(size_t)src * 512 + c];
    a0 += alpha * blo(v.x); a1 += alpha * bhi(v.x);
    a2 += alpha * blo(v.y); a3 += alpha * bhi(v.y);
    a4 += alpha * blo(v.z); a5 += alpha * bhi(v.z);
    a6 += alpha * blo(v.w); a7 += alpha * bhi(v.w);
  }
  float4* op = (float4*)&out[(size_t)n * 512 + c];
  op[0] = make_float4(a0, a1, a2, a3);
  op[1] = make_float4(a4, a5, a6, a7);
}

// ---------------- layer-1 aggregation, head-mean folded, wave/dst
__global__ __launch_bounds__(256) void aggregate_l1(const u16* __restrict__ xl,
    const float* __restrict__ esc, const int* __restrict__ ei,
    const int* __restrict__ offs, const int* __restrict__ eidx,
    float* __restrict__ out){
  int n = blockIdx.x * 4 + (threadIdx.x >> 6);
  int lane = threadIdx.x & 63;   // output channel
  int s = offs[n], e = offs[n + 1];
  float acc = 0.f;
  for (int i = s; i < e; i++){
    int eid = eidx[i];
    int src = ei[eid];
    float4 al = *(const float4*)&esc[eid * 4];
    const u16* xp = &xl[(size_t)src * 256 + lane];
    acc += al.x * 0.25f * b2f(xp[0]);
    acc += al.y * 0.25f * b2f(xp[64]);
    acc += al.z * 0.25f * b2f(xp[128]);
    acc += al.w * 0.25f * b2f(xp[192]);
  }
  out[(size_t)n * 64 + lane] = acc;
}

// ---------------- batchnorm reduce
__global__ void bn_reduce(const float* __restrict__ X, float* __restrict__ stats,
                          int Nr, int C, int rpb){
  int tid = threadIdx.x;
  int c = tid % C, sub = tid / C, step = blockDim.x / C;
  float s = 0.f, s2 = 0.f;
  int rend = min((int)((blockIdx.x + 1) * rpb), Nr);
  for (int r = blockIdx.x * rpb + sub; r < rend; r += step){
    float v = X[(size_t)r * C + c];
    s += v; s2 += v * v;
  }
  atomicAdd(&stats[c], s);
  atomicAdd(&stats[C + c], s2);
}

// ---------------- BN+ELU -> bf16 out (layer 0 path feeds MFMA GEMM)
__global__ __launch_bounds__(256) void bn_apply_bf(const float* __restrict__ X,
    const float* __restrict__ stats, const float* __restrict__ g,
    const float* __restrict__ b, u16* __restrict__ Xb, int total, int C, float invN){
  int idx = blockIdx.x * 256 + threadIdx.x;
  if (idx >= total) return;
  int c = idx % C;
  float mean = stats[c] * invN;
  float var = stats[C + c] * invN - mean * mean;
  float inv = rsqrtf(var + 1e-5f);
  float v = (X[idx] - mean) * inv * g[c] + b[c];
  Xb[idx] = fbf(elu(v));
}

// ---------------- BN+ELU fp32 in place (layer 1 path)
__global__ __launch_bounds__(256) void bn_apply(float* __restrict__ X,
    const float* __restrict__ stats, const float* __restrict__ g,
    const float* __restrict__ b, int total, int C, float invN){
  int idx = blockIdx.x * 256 + threadIdx.x;
  if (idx >= total) return;
  int c = idx % C;
  float mean = stats[c] * invN;
  float var = stats[C + c] * invN - mean * mean;
  float inv = rsqrtf(var + 1e-5f);
  float v = (X[idx] - mean) * inv * g[c] + b[c];
  X[idx] = elu(v);
}

// ---------------- per-graph mean pool (block per graph, no atomics)
__global__ __launch_bounds__(256) void pool_graph(const float* __restrict__ h1,
    const int* __restrict__ goffs, float* __restrict__ emb, float* __restrict__ out_emb){
  int b = blockIdx.x;
  int s = goffs[b], e = goffs[b + 1];
  int c = threadIdx.x & 63, sub = threadIdx.x >> 6;
  float acc = 0.f;
  for (int n = s + sub; n < e; n += 4) acc += h1[(size_t)n * 64 + c];
  __shared__ float red[4][64];
  red[sub][c] = acc;
  __syncthreads();
  if (sub == 0){
    float v = red[0][c] + red[1][c] + red[2][c] + red[3][c];
    v /= fmaxf((float)(e - s), 1.0f);
    emb[b * 64 + c] = v;
    out_emb[b * 64 + c] = v;
  }
}

// ---------------- fused classifier: emb -> z1 -> BN/ELU -> z2 -> BN/ELU -> logits
// One block, 256 threads. LDS: [0..4096) emb | [4096..12288) z1 chunk (64x128)
// phase3 overlay: [0..8448) z2 (64x132 padded). Partials at [12288..12800).
__global__ __launch_bounds__(256, 1) void classifier(
    const float* __restrict__ embg,
    const float* __restrict__ W1, const float* __restrict__ b1,
    const float* __restrict__ g1, const float* __restrict__ bb1,
    const float* __restrict__ W2, const float* __restrict__ b2,
    const float* __restrict__ g2, const float* __restrict__ bb2,
    const float* __restrict__ W3, const float* __restrict__ b3,
    float* __restrict__ out){
  __shared__ float smem[12800];
  float* emb = smem;              // 64*64
  float* z1  = smem + 4096;       // 64*128 (current chunk)
  float* z2  = smem;              // 64*132 (phase 3 overlay)
  float* ps  = smem + 12288;      // 256 partial sums
  float* ps2 = smem + 12544;      // 256 partial sumsq
  int t = threadIdx.x;
  int jj = t & 127;               // local channel
  int h  = t >> 7;                // batch half: rows [32h, 32h+32)
  for (int i = t; i < 4096; i += 256) emb[i] = embg[i];
  __syncthreads();

  float acc2[32];
  #pragma unroll
  for (int i = 0; i < 32; i++) acc2[i] = 0.f;

  for (int c = 0; c < 2; c++){
    int j = c * 128 + jj;         // global z1 channel
    // ---- phase 1: z1[:, j] for 32 rows ----
    float acc[32];
    float bias = b1[j];
    #pragma unroll
    for (int i = 0; i < 32; i++) acc[i] = bias;
    for (int k = 0; k < 64; k++){
      float w = W1[k * 256 + j];
      #pragma unroll
      for (int i = 0; i < 32; i++) acc[i] += emb[(32 * h + i) * 64 + k] * w;
    }
    float s = 0.f, s2 = 0.f;
    #pragma unroll
    for (int i = 0; i < 32; i++){ s += acc[i]; s2 += acc[i] * acc[i]; }
    ps[t] = s; ps2[t] = s2;
    __syncthreads();
    float S = s + ps[t ^ 128], S2 = s2 + ps2[t ^ 128];
    float mean = S * (1.f / 64.f);
    float var = S2 * (1.f / 64.f) - mean * mean;
    float inv = rsqrtf(var + 1e-5f);
    float sc = g1[j] * inv, sh = bb1[j] - mean * sc;
    #pragma unroll
    for (int i = 0; i < 32; i++)
      z1[(32 * h + i) * 128 + jj] = elu(acc[i] * sc + sh);
    __syncthreads();
    // ---- phase 2 partial: accumulate z2 contributions from this chunk ----
    for (int k = 0; k < 128; k++){
      float w = W2[(c * 128 + k) * 128 + jj];
      #pragma unroll
      for (int i = 0; i < 32; i++) acc2[i] += z1[(32 * h + i) * 128 + k] * w;
    }
    __syncthreads();   // chunk done before z1 overwritten next iter
  }

  // ---- BN2 + ELU -> z2 (overlay; all z1/emb reads complete) ----
  float bias2 = b2[jj];
  #pragma unroll
  for (int i = 0; i < 32; i++) acc2[i] += bias2;
  float s = 0.f, s2 = 0.f;
  #pragma unroll
  for (int i = 0; i < 32; i++){ s += acc2[i]; s2 += acc2[i] * acc2[i]; }
  ps[t] = s; ps2[t] = s2;
  __syncthreads();
  float S = s + ps[t ^ 128], S2 = s2 + ps2[t ^ 128];
  float mean = S * (1.f / 64.f);
  float var = S2 * (1.f / 64.f) - mean * mean;
  float inv = rsqrtf(var + 1e-5f);
  float sc = g2[jj] * inv, sh = bb2[jj] - mean * sc;
  __syncthreads();               // everyone past ps reads before z2 overlay write
  #pragma unroll
  for (int i = 0; i < 32; i++)
    z2[(32 * h + i) * 132 + jj] = elu(acc2[i] * sc + sh);
  __syncthreads();

  // ---- phase 3: logits ----
  if (t < 128){
    int o = t >> 6, b = t & 63;
    float a = b3[o];
    for (int j = 0; j < 128; j++) a += z2[b * 132 + j] * W3[j * 2 + o];
    out[b * 2 + o] = a;
  }
}

extern "C" void kernel_launch(void* const* d_in, const int* in_sizes, int n_in,
                              void* d_out, int out_size, void* d_ws, size_t ws_size,
                              hipStream_t stream){
  const float* x      = (const float*)d_in[0];
  const int*   ei     = (const int*)d_in[1];
  const float* ea     = (const float*)d_in[2];
  const int*   batch  = (const int*)d_in[3];
  const float* g0_wl  = (const float*)d_in[4];
  const float* g0_wr  = (const float*)d_in[5];
  const float* g0_we  = (const float*)d_in[6];
  const float* g0_att = (const float*)d_in[7];
  const float* bn0_g  = (const float*)d_in[9];
  const float* bn0_b  = (const float*)d_in[10];
  const float* g1_wl  = (const float*)d_in[11];
  const float* g1_wr  = (const float*)d_in[12];
  const float* g1_we  = (const float*)d_in[13];
  const float* g1_att = (const float*)d_in[14];
  const float* bn1_g  = (const float*)d_in[16];
  const float* bn1_b  = (const float*)d_in[17];
  const float* c_w1   = (const float*)d_in[18];
  const float* c_b1   = (const float*)d_in[19];
  const float* cbn1_g = (const float*)d_in[20];
  const float* cbn1_b = (const float*)d_in[21];
  const float* c_w2   = (const float*)d_in[22];
  const float* c_b2   = (const float*)d_in[23];
  const float* cbn2_g = (const float*)d_in[24];
  const float* cbn2_b = (const float*)d_in[25];
  const float* c_w3   = (const float*)d_in[26];
  const float* c_b3   = (const float*)d_in[27];
  float* out = (float*)d_out;
  float* ws = (float*)d_ws;

  u16* xb   = (u16*)(ws + XB);
  u16* xl0b = (u16*)(ws + XL0B);
  u16* xr0b = (u16*)(ws + XR0B);
  u16* h0b  = (u16*)(ws + H0B);
  u16* wt0a = (u16*)(ws + WTS);
  u16* wt0b = wt0a + 131072;
  u16* wt1a = wt0a + 262144;
  u16* wt1b = wt0a + 393216;
  int* offs   = (int*)(ws + CSRI);
  int* cursor = offs + (Nn + 1);
  int* eidx   = cursor + Nn;
  int* goffs  = eidx + Ee;          // B+1

  hipMemsetAsync(cursor, 0, Nn * sizeof(int), stream);
  hipMemsetAsync(ws + SMALL, 0, ZCNT * sizeof(float), stream);

  // ---- conversions ----
  conv_bf<<<(Nn * 256 / 4 + 255) / 256, 256, 0, stream>>>(x, xb, Nn * 256 / 4);
  conv_wt<<<512, 256, 0, stream>>>(g0_wl, wt0a, 256, 512);
  conv_wt<<<512, 256, 0, stream>>>(g0_wr, wt0b, 256, 512);
  conv_wt<<<512, 256, 0, stream>>>(g1_wl, wt1a, 512, 256);
  conv_wt<<<512, 256, 0, stream>>>(g1_wr, wt1b, 512, 256);

  // ---- CSR by destination + graph bounds ----
  csr_hist<<<(Ee + 255) / 256, 256, 0, stream>>>(ei, cursor);
  csr_scan<<<1, 1024, 0, stream>>>(offs, cursor);
  csr_fill<<<(Ee + 255) / 256, 256, 0, stream>>>(ei, cursor, eidx);
  graph_bounds<<<(Nn + 255) / 256, 256, 0, stream>>>(batch, goffs);

  // ---- layer 0 ----
  gemm_mfma<<<dim3(4, 157, 2), 256, 0, stream>>>(xb, wt0a, wt0b, xl0b, xr0b,
                                                 Nn, 256, 512);
  score_l0<<<Ee / 4, 256, 0, stream>>>(xl0b, xr0b, ea, g0_we, g0_att, ei, ws + ESC);
  softmax_dst<<<(Nn * 4 + 255) / 256, 256, 0, stream>>>(ws + ESC, offs, eidx);
  aggregate_l0<<<Nn / 4, 256, 0, stream>>>(xl0b, ws + ESC, ei, offs, eidx, ws + OUT0);
  bn_reduce<<<200, 512, 0, stream>>>(ws + OUT0, ws + BN0S, Nn, 512, 100);
  bn_apply_bf<<<40000, 256, 0, stream>>>(ws + OUT0, ws + BN0S, bn0_g, bn0_b, h0b,
                                         Nn * 512, 512, 1.f / Nn);
  // ---- layer 1 ----
  gemm_mfma<<<dim3(2, 157, 2), 256, 0, stream>>>(h0b, wt1a, wt1b, xl0b, xr0b,
                                                 Nn, 512, 256);
  score_l1<<<Ee / 4, 256, 0, stream>>>(xl0b, xr0b, ea, g1_we, g1_att, ei, ws + ESC);
  softmax_dst<<<(Nn * 4 + 255) / 256, 256, 0, stream>>>(ws + ESC, offs, eidx);
  aggregate_l1<<<Nn / 4, 256, 0, stream>>>(xl0b, ws + ESC, ei, offs, eidx, ws + OUT1);
  bn_reduce<<<50, 256, 0, stream>>>(ws + OUT1, ws + BN1S, Nn, 64, 400);
  bn_apply<<<5000, 256, 0, stream>>>(ws + OUT1, ws + BN1S, bn1_g, bn1_b,
                                     Nn * 64, 64, 1.f / Nn);
  // ---- pool + fused classifier ----
  pool_graph<<<Bb, 256, 0, stream>>>(ws + OUT1, goffs, ws + EMB, out + 128);
  classifier<<<1, 256, 0, stream>>>(ws + EMB, c_w1, c_b1, cbn1_g, cbn1_b,
                                    c_w2, c_b2, cbn2_g, cbn2_b, c_w3, c_b3, out);
}